// Round 7
// baseline (320.493 us; speedup 1.0000x reference)
//
#include <hip/hip_runtime.h>
#include <math.h>

// Problem constants
#define B_   64
#define S_   64
#define W_   12
#define V_   32000
#define SYM_ 128
#define HID_ 256
#define E_   64
#define R_   32

// ---------------------------------------------------------------------------
// K0: zero the MLP output buffers (atomic accumulation targets)
// ---------------------------------------------------------------------------
__global__ __launch_bounds__(256) void k_zero(float* __restrict__ p, int n4) {
  int i = blockIdx.x * 256 + threadIdx.x;
  if (i < n4) ((float4*)p)[i] = make_float4(0.f, 0.f, 0.f, 0.f);
}

// ---------------------------------------------------------------------------
// K1: embedding sums for story (rows 0..4095) and query (rows 4096..4159)
// ---------------------------------------------------------------------------
__global__ __launch_bounds__(128) void k_embed(
    const int* __restrict__ story, const int* __restrict__ query,
    const float* __restrict__ we, const float* __restrict__ pe,
    float* __restrict__ X) {
  int row = blockIdx.x;
  int e = threadIdx.x;
  const int* idx = (row < 4096) ? story + row * W_ : query + (row - 4096) * W_;
  float acc = 0.f;
#pragma unroll
  for (int w = 0; w < W_; ++w)
    acc = fmaf(we[(long)idx[w] * SYM_ + e], pe[w * SYM_ + e], acc);
  X[row * SYM_ + e] = acc;
}

// ---------------------------------------------------------------------------
// K2 v3: MLP with p-chunk split across blocks.
// Block = (tile, head, p): tile of 32 rows, head 0..4, hidden chunk p (64 c).
// Layer1: X read DIRECT from global (float4 along k, L1-broadcast); no XT LDS.
// Layer2 partials accumulated to global via atomicAdd (zero-initialized).
// Bias b2 added by the p==0 block only.
// ---------------------------------------------------------------------------
__global__ __launch_bounds__(256) void k_mlp(
    const float* __restrict__ X,
    const float* __restrict__ ueW1, const float* __restrict__ ueb1,
    const float* __restrict__ ueW2, const float* __restrict__ ueb2,
    const float* __restrict__ urW1, const float* __restrict__ urb1,
    const float* __restrict__ urW2, const float* __restrict__ urb2,
    const float* __restrict__ ieW1, const float* __restrict__ ieb1,
    const float* __restrict__ ieW2, const float* __restrict__ ieb2,
    const float* __restrict__ irW1, const float* __restrict__ irb1,
    const float* __restrict__ irW2, const float* __restrict__ irb2,
    float* __restrict__ oE0, float* __restrict__ oE1,
    float* __restrict__ oR0, float* __restrict__ oR1, float* __restrict__ oR2) {
  __shared__ float HT[64 * 34];  // [c][row], stride 34 (even, for float2)

  int tile = blockIdx.x / 20;
  int rem = blockIdx.x % 20;
  int h = rem >> 2;
  int p = rem & 3;
  int rowbase = tile * 32;
  bool isQ = (rowbase >= 4096);
  bool isE = (h < 2);
  const float* eW1 = isQ ? ieW1 : ueW1;
  const float* eb1 = isQ ? ieb1 : ueb1;
  const float* eW2 = isQ ? ieW2 : ueW2;
  const float* eb2 = isQ ? ieb2 : ueb2;
  const float* rW1 = isQ ? irW1 : urW1;
  const float* rb1 = isQ ? irb1 : urb1;
  const float* rW2 = isQ ? irW2 : urW2;
  const float* rb2 = isQ ? irb2 : urb2;
  const float* W1 = isE ? eW1 + h * (SYM_ * HID_) : rW1 + (h - 2) * (SYM_ * HID_);
  const float* b1 = isE ? eb1 + h * HID_ : rb1 + (h - 2) * HID_;
  const float* W2 = isE ? eW2 + h * (HID_ * E_) : rW2 + (h - 2) * (HID_ * R_);
  const float* b2 = isE ? eb2 + h * E_ : rb2 + (h - 2) * R_;
  float* out = (h == 0) ? oE0 : (h == 1) ? oE1 : (h == 2) ? oR0 : (h == 3) ? oR1 : oR2;

  int tid = threadIdx.x;
  int tr = tid >> 4, tc = tid & 15;
  int cbase = p * 64;
  const float* x0p = X + (long)(rowbase + 2 * tr) * SYM_;
  const float* x1p = x0p + SYM_;
  const float* W1p = W1 + cbase + 4 * tc;

  // ---- layer 1: a[2 rows][4 cols] over k=0..127 ----
  float a0[4] = {}, a1[4] = {};
#pragma unroll 2
  for (int kb = 0; kb < 32; ++kb) {
    float4 xa = *(const float4*)(x0p + 4 * kb);
    float4 xb = *(const float4*)(x1p + 4 * kb);
    float4 w0 = *(const float4*)(W1p + (4 * kb + 0) * HID_);
    float4 w1 = *(const float4*)(W1p + (4 * kb + 1) * HID_);
    float4 w2 = *(const float4*)(W1p + (4 * kb + 2) * HID_);
    float4 w3 = *(const float4*)(W1p + (4 * kb + 3) * HID_);
    float X0[4] = {xa.x, xa.y, xa.z, xa.w};
    float X1[4] = {xb.x, xb.y, xb.z, xb.w};
    float4 Wv[4] = {w0, w1, w2, w3};
#pragma unroll
    for (int q = 0; q < 4; ++q) {
      float4 w = Wv[q];
      a0[0] = fmaf(X0[q], w.x, a0[0]); a0[1] = fmaf(X0[q], w.y, a0[1]);
      a0[2] = fmaf(X0[q], w.z, a0[2]); a0[3] = fmaf(X0[q], w.w, a0[3]);
      a1[0] = fmaf(X1[q], w.x, a1[0]); a1[1] = fmaf(X1[q], w.y, a1[1]);
      a1[2] = fmaf(X1[q], w.z, a1[2]); a1[3] = fmaf(X1[q], w.w, a1[3]);
    }
  }
  // ---- tanh -> HT ----
  float4 b1v = *(const float4*)(b1 + cbase + 4 * tc);
  float b1s[4] = {b1v.x, b1v.y, b1v.z, b1v.w};
#pragma unroll
  for (int j = 0; j < 4; ++j) {
    float h0 = tanhf(a0[j] + b1s[j]);
    float h1 = tanhf(a1[j] + b1s[j]);
    *(float2*)&HT[(4 * tc + j) * 34 + 2 * tr] = make_float2(h0, h1);
  }
  __syncthreads();

  // ---- layer 2 partial over this chunk's 64 c ----
  int r0 = rowbase + 2 * tr;
  if (isE) {
    float acc0[4] = {}, acc1[4] = {};
#pragma unroll 4
    for (int c = 0; c < 64; ++c) {
      float2 hh = *(const float2*)&HT[c * 34 + 2 * tr];
      float4 w4 = *(const float4*)(W2 + (long)(cbase + c) * E_ + 4 * tc);
      acc0[0] = fmaf(hh.x, w4.x, acc0[0]); acc0[1] = fmaf(hh.x, w4.y, acc0[1]);
      acc0[2] = fmaf(hh.x, w4.z, acc0[2]); acc0[3] = fmaf(hh.x, w4.w, acc0[3]);
      acc1[0] = fmaf(hh.y, w4.x, acc1[0]); acc1[1] = fmaf(hh.y, w4.y, acc1[1]);
      acc1[2] = fmaf(hh.y, w4.z, acc1[2]); acc1[3] = fmaf(hh.y, w4.w, acc1[3]);
    }
    if (p == 0) {
      float4 b2v = *(const float4*)(b2 + 4 * tc);
      acc0[0] += b2v.x; acc0[1] += b2v.y; acc0[2] += b2v.z; acc0[3] += b2v.w;
      acc1[0] += b2v.x; acc1[1] += b2v.y; acc1[2] += b2v.z; acc1[3] += b2v.w;
    }
#pragma unroll
    for (int j = 0; j < 4; ++j) {
      atomicAdd(out + (long)r0 * E_ + 4 * tc + j, acc0[j]);
      atomicAdd(out + (long)(r0 + 1) * E_ + 4 * tc + j, acc1[j]);
    }
  } else {
    float acc0[2] = {}, acc1[2] = {};
#pragma unroll 4
    for (int c = 0; c < 64; ++c) {
      float2 hh = *(const float2*)&HT[c * 34 + 2 * tr];
      float2 w2 = *(const float2*)(W2 + (long)(cbase + c) * R_ + 2 * tc);
      acc0[0] = fmaf(hh.x, w2.x, acc0[0]); acc0[1] = fmaf(hh.x, w2.y, acc0[1]);
      acc1[0] = fmaf(hh.y, w2.x, acc1[0]); acc1[1] = fmaf(hh.y, w2.y, acc1[1]);
    }
    if (p == 0) {
      float2 b2v = *(const float2*)(b2 + 2 * tc);
      acc0[0] += b2v.x; acc0[1] += b2v.y;
      acc1[0] += b2v.x; acc1[1] += b2v.y;
    }
#pragma unroll
    for (int j = 0; j < 2; ++j) {
      atomicAdd(out + (long)r0 * R_ + 2 * tc + j, acc0[j]);
      atomicAdd(out + (long)(r0 + 1) * R_ + 2 * tc + j, acc1[j]);
    }
  }
}

// ---------------------------------------------------------------------------
// K_gram: W[b,m,s,j] = (sE_s . jE_j) * (sR_s . jR_j)   (unchanged)
// ---------------------------------------------------------------------------
__global__ __launch_bounds__(256) void k_gram(
    const float* __restrict__ e1, const float* __restrict__ e2,
    const float* __restrict__ r1, const float* __restrict__ r2,
    const float* __restrict__ r3, float* __restrict__ Wc) {
  int b = blockIdx.x / 9, m = blockIdx.x % 9;
  const float* sE = ((m < 6) ? e1 : e2) + (long)b * S_ * E_;
  const float* jE = ((m == 2 || m == 5 || m == 8) ? e2 : e1) + (long)b * S_ * E_;
  int sk = m / 3, jk = m % 3;
  const float* sR = ((sk == 0) ? r1 : (sk == 1) ? r2 : r3) + (long)b * S_ * R_;
  const float* jR = ((jk == 0) ? r1 : (jk == 1) ? r2 : r3) + (long)b * S_ * R_;

  __shared__ float Es[64][68], Ej[64][68], Rs[64][36], Rj[64][36];
  int tid = threadIdx.x;
  for (int i = tid; i < 1024; i += 256) {
    int row = i >> 4, c = i & 15;
    *(float4*)&Es[row][4 * c] = *(const float4*)(sE + row * 64 + 4 * c);
    *(float4*)&Ej[row][4 * c] = *(const float4*)(jE + row * 64 + 4 * c);
  }
  for (int i = tid; i < 512; i += 256) {
    int row = i >> 3, c = i & 7;
    *(float4*)&Rs[row][4 * c] = *(const float4*)(sR + row * 32 + 4 * c);
    *(float4*)&Rj[row][4 * c] = *(const float4*)(jR + row * 32 + 4 * c);
  }
  __syncthreads();

  int s0 = (tid >> 4) * 4, j0 = (tid & 15) * 4;
  float ed[4][4] = {}, rd[4][4] = {};
#pragma unroll 4
  for (int k = 0; k < 16; ++k) {
    float4 es[4], ej[4];
#pragma unroll
    for (int i = 0; i < 4; ++i) {
      es[i] = *(const float4*)&Es[s0 + i][4 * k];
      ej[i] = *(const float4*)&Ej[j0 + i][4 * k];
    }
#pragma unroll
    for (int i = 0; i < 4; ++i)
#pragma unroll
      for (int j = 0; j < 4; ++j)
        ed[i][j] = fmaf(es[i].x, ej[j].x, fmaf(es[i].y, ej[j].y,
                   fmaf(es[i].z, ej[j].z, fmaf(es[i].w, ej[j].w, ed[i][j]))));
  }
#pragma unroll 4
  for (int k = 0; k < 8; ++k) {
    float4 rs[4], rj[4];
#pragma unroll
    for (int i = 0; i < 4; ++i) {
      rs[i] = *(const float4*)&Rs[s0 + i][4 * k];
      rj[i] = *(const float4*)&Rj[j0 + i][4 * k];
    }
#pragma unroll
    for (int i = 0; i < 4; ++i)
#pragma unroll
      for (int j = 0; j < 4; ++j)
        rd[i][j] = fmaf(rs[i].x, rj[j].x, fmaf(rs[i].y, rj[j].y,
                   fmaf(rs[i].z, rj[j].z, fmaf(rs[i].w, rj[j].w, rd[i][j]))));
  }
  float* wout = Wc + (((long)(b * 9 + m) * 64) * 64);
#pragma unroll
  for (int i = 0; i < 4; ++i) {
    float4 o4 = make_float4(ed[i][0] * rd[i][0], ed[i][1] * rd[i][1],
                            ed[i][2] * rd[i][2], ed[i][3] * rd[i][3]);
    *(float4*)(wout + (s0 + i) * 64 + j0) = o4;
  }
}

// ---------------------------------------------------------------------------
// K_scan v5 (outer-product, no reductions) — unchanged from R6
// ---------------------------------------------------------------------------
#define WCOMP(v, jj) ((jj) == 0 ? (v).x : (jj) == 1 ? (v).y : (jj) == 2 ? (v).z : (v).w)

__global__ __launch_bounds__(256) void k_scan(
    const float* __restrict__ e1g, const float* __restrict__ e2g,
    const float* __restrict__ Wc, float4* __restrict__ acd) {
  int blk = blockIdx.x;
  int b = blk & 63;
  int g = blk >> 6;                // 0..7
  int wv = threadIdx.x >> 6;       // 0..3
  int lane = threadIdx.x & 63;     // = s
  int f0 = g * 8 + wv * 2;
  int f1 = f0 + 1;
  const float* Wb = Wc + (long)b * 9 * 4096 + lane * 64;
  long eoff = ((long)b * 64 + lane) * 64;
  float e1x = e1g[eoff + f0], e1y = e1g[eoff + f1];
  float e2x = e2g[eoff + f0], e2y = e2g[eoff + f1];

  float pW0 = 0.f, pM0 = 0.f, pB0 = 0.f;
  float pW1 = 0.f, pM1 = 0.f, pB1 = 0.f;
  float ca0 = e2x, cc0 = 0.f, cd0 = e1x;
  float ca1 = e2y, cc1 = 0.f, cd1 = e1y;
  float ka0 = 0.f, kc0 = 0.f, kd0 = 0.f;
  float ka1 = 0.f, kc1 = 0.f, kd1 = 0.f;

  for (int j0 = 0; j0 < 64; j0 += 4) {
    float4 w[9];
#pragma unroll
    for (int m = 0; m < 9; ++m)
      w[m] = *(const float4*)(Wb + m * 4096 + j0);
#pragma unroll
    for (int jj = 0; jj < 4; ++jj) {
      int j = j0 + jj;
      float aj0 = __int_as_float(__builtin_amdgcn_readlane(__float_as_int(ca0), j));
      float cj0 = __int_as_float(__builtin_amdgcn_readlane(__float_as_int(cc0), j));
      float dj0 = __int_as_float(__builtin_amdgcn_readlane(__float_as_int(cd0), j));
      float aj1 = __int_as_float(__builtin_amdgcn_readlane(__float_as_int(ca1), j));
      float cj1 = __int_as_float(__builtin_amdgcn_readlane(__float_as_int(cc1), j));
      float dj1 = __int_as_float(__builtin_amdgcn_readlane(__float_as_int(cd1), j));
      bool own = (lane == j);
      ka0 = own ? ca0 : ka0; kc0 = own ? cc0 : kc0; kd0 = own ? cd0 : kd0;
      ka1 = own ? ca1 : ka1; kc1 = own ? cc1 : kc1; kd1 = own ? cd1 : kd1;
      float wa = WCOMP(w[0], jj), wc = WCOMP(w[1], jj), wd = WCOMP(w[2], jj);
      float ma = WCOMP(w[3], jj), mc = WCOMP(w[4], jj), md = WCOMP(w[5], jj);
      float ba = WCOMP(w[6], jj), bc = WCOMP(w[7], jj), bd = WCOMP(w[8], jj);
      pW0 = fmaf(wa, aj0, pW0); pW0 = fmaf(wc, cj0, pW0); pW0 = fmaf(wd, dj0, pW0);
      pM0 = fmaf(ma, aj0, pM0); pM0 = fmaf(mc, cj0, pM0); pM0 = fmaf(md, dj0, pM0);
      pB0 = fmaf(ba, aj0, pB0); pB0 = fmaf(bc, cj0, pB0); pB0 = fmaf(bd, dj0, pB0);
      pW1 = fmaf(wa, aj1, pW1); pW1 = fmaf(wc, cj1, pW1); pW1 = fmaf(wd, dj1, pW1);
      pM1 = fmaf(ma, aj1, pM1); pM1 = fmaf(mc, cj1, pM1); pM1 = fmaf(md, dj1, pM1);
      pB1 = fmaf(ba, aj1, pB1); pB1 = fmaf(bc, cj1, pB1); pB1 = fmaf(bd, dj1, pB1);
      ca0 = e2x - pW0; cc0 = pW0 - pM0; cd0 = e1x - pB0;
      ca1 = e2y - pW1; cc1 = pW1 - pM1; cd1 = e1y - pB1;
    }
  }
  acd[eoff + f0] = make_float4(ka0, kc0, kd0, 0.f);
  acd[eoff + f1] = make_float4(ka1, kc1, kd1, 0.f);
}

// ---------------------------------------------------------------------------
// K_infer v2: 1024 threads per b. hist staged once to SoA LDS (stride 65);
// u-dots 8-way parallel per dot; y-phase 16-way per f; LN on wave 0.
// ---------------------------------------------------------------------------
__global__ __launch_bounds__(1024) void k_infer(
    const float4* __restrict__ acd,
    const float* __restrict__ e1, const float* __restrict__ e2,
    const float* __restrict__ r1, const float* __restrict__ r2,
    const float* __restrict__ r3,
    const float* __restrict__ qe1, const float* __restrict__ qr1,
    const float* __restrict__ qr2, const float* __restrict__ qr3,
    const float* __restrict__ lng, const float* __restrict__ lnb,
    float* __restrict__ isum) {
  int b = blockIdx.x, tid = threadIdx.x;
  __shared__ float hista[64 * 65], histc[64 * 65], histd[64 * 65];
  __shared__ float vlds[9 * 64];
  __shared__ float ivec[64];
  __shared__ float u1s[64], u2s[64];
  __shared__ float dsc[64];

  {
    const float4* ab = acd + (long)b * 4096;
    for (int idx = tid; idx < 4096; idx += 1024) {
      float4 hv = ab[idx];
      int j = idx >> 6, f = idx & 63;
      hista[j * 65 + f] = hv.x;
      histc[j * 65 + f] = hv.y;
      histd[j * 65 + f] = hv.z;
    }
  }
  if (tid < 576) {
    int pk = tid >> 6, j = tid & 63;
    int p = pk / 3, k = pk % 3;
    const float* rv = ((k == 0) ? r1 : (k == 1) ? r2 : r3) + ((long)b * 64 + j) * 32;
    const float* q = ((p == 0) ? qr1 : (p == 1) ? qr2 : qr3) + b * 32;
    float acc = 0.f;
#pragma unroll
    for (int t = 0; t < 8; ++t) {
      float4 rv4 = *(const float4*)(rv + 4 * t);
      float4 q4 = *(const float4*)(q + 4 * t);
      acc = fmaf(rv4.x, q4.x, fmaf(rv4.y, q4.y,
            fmaf(rv4.z, q4.z, fmaf(rv4.w, q4.w, acc))));
    }
    vlds[pk * 64 + j] = acc;
  }
  if (tid < 64) ivec[tid] = qe1[b * 64 + tid];
  __syncthreads();

  int f = tid >> 4, jsl = tid & 15;
  int dotd = tid >> 3, dt = tid & 7;
  int which = dotd >> 6, dj = dotd & 63;
  const float* erow = (which ? e2 : e1) + ((long)b * 64 + dj) * 64 + dt * 8;
  float isacc = 0.f;
  for (int p = 0; p < 3; ++p) {
    // u-dots: 128 dots x 8 threads each
    {
      float acc = 0.f;
#pragma unroll
      for (int t = 0; t < 8; ++t)
        acc = fmaf(erow[t], ivec[dt * 8 + t], acc);
      acc += __shfl_xor(acc, 1, 64);
      acc += __shfl_xor(acc, 2, 64);
      acc += __shfl_xor(acc, 4, 64);
      if (dt == 0) { if (which) u2s[dj] = acc; else u1s[dj] = acc; }
    }
    __syncthreads();
    // y[f]: 64 f x 16 threads, 4 j each
    float part = 0.f;
#pragma unroll
    for (int i = 0; i < 4; ++i) {
      int j = jsl * 4 + i;
      float ca = u1s[j] * vlds[(p * 3 + 0) * 64 + j];
      float cc = u1s[j] * vlds[(p * 3 + 1) * 64 + j];
      float cd = u2s[j] * vlds[(p * 3 + 2) * 64 + j];
      part = fmaf(ca, hista[j * 65 + f],
             fmaf(cc, histc[j * 65 + f],
             fmaf(cd, histd[j * 65 + f], part)));
    }
    part += __shfl_xor(part, 1, 64);
    part += __shfl_xor(part, 2, 64);
    part += __shfl_xor(part, 4, 64);
    part += __shfl_xor(part, 8, 64);
    if (jsl == 0) dsc[f] = part;
    __syncthreads();
    if (tid < 64) {
      float v = dsc[tid];
      float mu = v;
#pragma unroll
      for (int mm = 1; mm <= 32; mm <<= 1) mu += __shfl_xor(mu, mm, 64);
      mu *= (1.f / 64.f);
      float d = v - mu;
      float vr = d * d;
#pragma unroll
      for (int mm = 1; mm <= 32; mm <<= 1) vr += __shfl_xor(vr, mm, 64);
      vr *= (1.f / 64.f);
      float iv = d * (1.f / sqrtf(vr + 1e-5f)) * lng[p * 64 + tid] + lnb[p * 64 + tid];
      ivec[tid] = iv;
      isacc += iv;
    }
    __syncthreads();
  }
  if (tid < 64) isum[b * 64 + tid] = isacc;
}

// ---------------------------------------------------------------------------
// K5: out[b,v] = sum_e isum[b,e] * Z[e,v]   (unchanged)
// ---------------------------------------------------------------------------
__global__ __launch_bounds__(256) void k_final(
    const float* __restrict__ isum, const float* __restrict__ Zm,
    float* __restrict__ out) {
  __shared__ float isT[64 * 68];
  int tid = threadIdx.x;
  for (int i = tid; i < 4096; i += 256) {
    int bb = i >> 6, e = i & 63;
    isT[e * 68 + bb] = isum[i];
  }
  __syncthreads();
  int tr = tid >> 4, tc = tid & 15;
  int v0 = blockIdx.x * 64 + tc * 4;
  float acc[4][4] = {};
#pragma unroll 2
  for (int e = 0; e < 64; ++e) {
    float4 a4 = *(const float4*)&isT[e * 68 + 4 * tr];
    float4 z4 = *(const float4*)(Zm + (long)e * V_ + v0);
    float as[4] = {a4.x, a4.y, a4.z, a4.w};
    float zs[4] = {z4.x, z4.y, z4.z, z4.w};
#pragma unroll
    for (int i = 0; i < 4; ++i)
#pragma unroll
      for (int j = 0; j < 4; ++j) acc[i][j] = fmaf(as[i], zs[j], acc[i][j]);
  }
#pragma unroll
  for (int i = 0; i < 4; ++i) {
    float4 o4 = make_float4(acc[i][0], acc[i][1], acc[i][2], acc[i][3]);
    *(float4*)(out + (long)(4 * tr + i) * V_ + v0) = o4;
  }
}

// ---------------------------------------------------------------------------
extern "C" void kernel_launch(void* const* d_in, const int* in_sizes, int n_in,
                              void* d_out, int out_size, void* d_ws, size_t ws_size,
                              hipStream_t stream) {
  const int* story = (const int*)d_in[0];
  const int* query = (const int*)d_in[1];
  const float* we = (const float*)d_in[2];
  const float* pe = (const float*)d_in[3];
  const float* ueW1 = (const float*)d_in[4];
  const float* ueb1 = (const float*)d_in[5];
  const float* ueW2 = (const float*)d_in[6];
  const float* ueb2 = (const float*)d_in[7];
  const float* urW1 = (const float*)d_in[8];
  const float* urb1 = (const float*)d_in[9];
  const float* urW2 = (const float*)d_in[10];
  const float* urb2 = (const float*)d_in[11];
  const float* ieW1 = (const float*)d_in[12];
  const float* ieb1 = (const float*)d_in[13];
  const float* ieW2 = (const float*)d_in[14];
  const float* ieb2 = (const float*)d_in[15];
  const float* irW1 = (const float*)d_in[16];
  const float* irb1 = (const float*)d_in[17];
  const float* irW2 = (const float*)d_in[18];
  const float* irb2 = (const float*)d_in[19];
  const float* lng = (const float*)d_in[20];
  const float* lnb = (const float*)d_in[21];
  const float* Zm = (const float*)d_in[22];

  float* ws = (float*)d_ws;
  float* X = ws;                        // 4160*128 = 532480
  float* e1 = X + 532480;               // 4160*64  = 266240
  float* e2 = e1 + 266240;              // 266240
  float* r1 = e2 + 266240;              // 4160*32  = 133120
  float* r2 = r1 + 133120;              // 133120
  float* r3 = r2 + 133120;              // 133120
  float* isum = r3 + 133120;            // 4096
  float* Wcoef = isum + 4096;           // 9*64*4096 = 2359296
  float4* acd = (float4*)(Wcoef + 2359296);  // 64*64*64 float4 = 4 MB
  float* qe1 = e1 + 4096 * 64;
  float* qr1 = r1 + 4096 * 32;
  float* qr2 = r2 + 4096 * 32;
  float* qr3 = r3 + 4096 * 32;
  float* outF = (float*)d_out;

  // zero the atomic-accumulated e/r buffers: e1..r3 contiguous = 931840 floats
  k_zero<<<(931840 / 4 + 255) / 256, 256, 0, stream>>>(e1, 931840 / 4);
  k_embed<<<4160, 128, 0, stream>>>(story, query, we, pe, X);
  k_mlp<<<130 * 20, 256, 0, stream>>>(X, ueW1, ueb1, ueW2, ueb2,
                                      urW1, urb1, urW2, urb2,
                                      ieW1, ieb1, ieW2, ieb2,
                                      irW1, irb1, irW2, irb2,
                                      e1, e2, r1, r2, r3);
  k_gram<<<64 * 9, 256, 0, stream>>>(e1, e2, r1, r2, r3, Wcoef);
  k_scan<<<512, 256, 0, stream>>>(e1, e2, Wcoef, acd);
  k_infer<<<B_, 1024, 0, stream>>>(acd, e1, e2, r1, r2, r3, qe1, qr1, qr2, qr3,
                                   lng, lnb, isum);
  k_final<<<V_ / 64, 256, 0, stream>>>(isum, Zm, outF);
}

// Round 8
// 223.803 us; speedup vs baseline: 1.4320x; 1.4320x over previous
//
#include <hip/hip_runtime.h>
#include <math.h>

// Problem constants
#define B_   64
#define S_   64
#define W_   12
#define V_   32000
#define SYM_ 128
#define HID_ 256
#define E_   64
#define R_   32

// ---------------------------------------------------------------------------
// K1: embedding sums for story (rows 0..4095) and query (rows 4096..4159)
// ---------------------------------------------------------------------------
__global__ __launch_bounds__(128) void k_embed(
    const int* __restrict__ story, const int* __restrict__ query,
    const float* __restrict__ we, const float* __restrict__ pe,
    float* __restrict__ X) {
  int row = blockIdx.x;
  int e = threadIdx.x;
  const int* idx = (row < 4096) ? story + row * W_ : query + (row - 4096) * W_;
  float acc = 0.f;
#pragma unroll
  for (int w = 0; w < W_; ++w)
    acc = fmaf(we[(long)idx[w] * SYM_ + e], pe[w * SYM_ + e], acc);
  X[row * SYM_ + e] = acc;
}

// ---------------------------------------------------------------------------
// K2 v5: LDS-GEMM MLP. Block = (32-row tile, head); 650 blocks, 256 thr.
// k-chunked: stage XT-chunk [32k][32row] + W1-chunk [32k][256c] (both via
// DENSE contiguous loads), FMA from LDS (broadcast reads, conflict-free).
// H lives in LDS (overlaying the staging region); layer2 from LDS + W2.
// Thread = (tr=tid>>5: 4 rows, tc=tid&31: 8 cols). No atomics.
// ---------------------------------------------------------------------------
__global__ __launch_bounds__(256) void k_mlp(
    const float* __restrict__ X,
    const float* __restrict__ ueW1, const float* __restrict__ ueb1,
    const float* __restrict__ ueW2, const float* __restrict__ ueb2,
    const float* __restrict__ urW1, const float* __restrict__ urb1,
    const float* __restrict__ urW2, const float* __restrict__ urb2,
    const float* __restrict__ ieW1, const float* __restrict__ ieb1,
    const float* __restrict__ ieW2, const float* __restrict__ ieb2,
    const float* __restrict__ irW1, const float* __restrict__ irb1,
    const float* __restrict__ irW2, const float* __restrict__ irb2,
    float* __restrict__ oE0, float* __restrict__ oE1,
    float* __restrict__ oR0, float* __restrict__ oR1, float* __restrict__ oR2) {
  // SM layout: staging phase: XTc [0,1152) stride 36; W1L [1152, 9344)
  //            H phase: HT [0, 9216) = [256 c][36] (overlays; barrier-guarded)
  __shared__ float SM[9344];
  float* W1L = SM + 1152;

  int h = blockIdx.x % 5;
  int tile = blockIdx.x / 5;
  int rowbase = tile * 32;
  bool isQ = (rowbase >= 4096);
  bool isE = (h < 2);
  const float* W1 = isE ? (isQ ? ieW1 : ueW1) + h * (SYM_ * HID_)
                        : (isQ ? irW1 : urW1) + (h - 2) * (SYM_ * HID_);
  const float* b1 = isE ? (isQ ? ieb1 : ueb1) + h * HID_
                        : (isQ ? irb1 : urb1) + (h - 2) * HID_;
  const float* W2 = isE ? (isQ ? ieW2 : ueW2) + h * (HID_ * E_)
                        : (isQ ? irW2 : urW2) + (h - 2) * (HID_ * R_);
  const float* b2 = isE ? (isQ ? ieb2 : ueb2) + h * E_
                        : (isQ ? irb2 : urb2) + (h - 2) * R_;
  float* out = (h == 0) ? oE0 : (h == 1) ? oE1 : (h == 2) ? oR0 : (h == 3) ? oR1 : oR2;

  int tid = threadIdx.x;
  int tr = tid >> 5;   // 0..7 -> rows 4tr..4tr+3
  int tc = tid & 31;   // 0..31 -> cols 8tc..8tc+7

  float a[4][8];
#pragma unroll
  for (int i = 0; i < 4; ++i)
#pragma unroll
    for (int j = 0; j < 8; ++j) a[i][j] = 0.f;

  for (int kc = 0; kc < 4; ++kc) {
    __syncthreads();
    // stage XTc: 32 rows x 32 k, transposed to [k][row] stride 36.
    {
      int i = tid;  // 256 float4 = 1024 floats
      int row = i >> 3, k4 = (i & 7) * 4;
      float4 v = *(const float4*)(X + (long)(rowbase + row) * SYM_ + kc * 32 + k4);
      SM[(k4 + 0) * 36 + row] = v.x;
      SM[(k4 + 1) * 36 + row] = v.y;
      SM[(k4 + 2) * 36 + row] = v.z;
      SM[(k4 + 3) * 36 + row] = v.w;
    }
    // stage W1L: rows kc*32..+31 x 256 c = 8192 contiguous floats (dense).
    {
      const float* src = W1 + kc * 32 * HID_;
#pragma unroll
      for (int i = 0; i < 8; ++i)
        *(float4*)&W1L[(tid + 256 * i) * 4] = *(const float4*)(src + (tid + 256 * i) * 4);
    }
    __syncthreads();
#pragma unroll 4
    for (int k = 0; k < 32; ++k) {
      float4 xa = *(const float4*)&SM[k * 36 + 4 * tr];
      float4 w0 = *(const float4*)&W1L[k * 256 + 8 * tc];
      float4 w1 = *(const float4*)&W1L[k * 256 + 8 * tc + 4];
      float xs[4] = {xa.x, xa.y, xa.z, xa.w};
      float ws[8] = {w0.x, w0.y, w0.z, w0.w, w1.x, w1.y, w1.z, w1.w};
#pragma unroll
      for (int i = 0; i < 4; ++i)
#pragma unroll
        for (int j = 0; j < 8; ++j) a[i][j] = fmaf(xs[i], ws[j], a[i][j]);
    }
  }
  __syncthreads();  // staging region dead; safe to write HT
  // bias + tanh -> HT[c][row] stride 36
  {
    float4 bA = *(const float4*)(b1 + 8 * tc);
    float4 bB = *(const float4*)(b1 + 8 * tc + 4);
    float b1s[8] = {bA.x, bA.y, bA.z, bA.w, bB.x, bB.y, bB.z, bB.w};
#pragma unroll
    for (int j = 0; j < 8; ++j) {
      float4 hv = make_float4(tanhf(a[0][j] + b1s[j]), tanhf(a[1][j] + b1s[j]),
                              tanhf(a[2][j] + b1s[j]), tanhf(a[3][j] + b1s[j]));
      *(float4*)&SM[(8 * tc + j) * 36 + 4 * tr] = hv;
    }
  }
  __syncthreads();
  // layer 2
  int r0 = rowbase + 4 * tr;
  if (isE) {
    float acc0[4] = {}, acc1[4] = {};
#pragma unroll 4
    for (int c = 0; c < 256; ++c) {
      float4 h4 = *(const float4*)&SM[c * 36 + 4 * tr];
      float2 w2 = *(const float2*)(W2 + (long)c * E_ + 2 * tc);
      float hs[4] = {h4.x, h4.y, h4.z, h4.w};
#pragma unroll
      for (int i = 0; i < 4; ++i) {
        acc0[i] = fmaf(hs[i], w2.x, acc0[i]);
        acc1[i] = fmaf(hs[i], w2.y, acc1[i]);
      }
    }
    float2 b2v = *(const float2*)(b2 + 2 * tc);
#pragma unroll
    for (int i = 0; i < 4; ++i)
      *(float2*)(out + (long)(r0 + i) * E_ + 2 * tc) =
          make_float2(acc0[i] + b2v.x, acc1[i] + b2v.y);
  } else {
    float acc0[4] = {};
#pragma unroll 4
    for (int c = 0; c < 256; ++c) {
      float4 h4 = *(const float4*)&SM[c * 36 + 4 * tr];
      float w = W2[(long)c * R_ + tc];
      float hs[4] = {h4.x, h4.y, h4.z, h4.w};
#pragma unroll
      for (int i = 0; i < 4; ++i) acc0[i] = fmaf(hs[i], w, acc0[i]);
    }
    float b2v = b2[tc];
#pragma unroll
    for (int i = 0; i < 4; ++i)
      out[(long)(r0 + i) * R_ + tc] = acc0[i] + b2v;
  }
}

// ---------------------------------------------------------------------------
// K_gram v2: writes TRANSPOSED Wt[b][m][j][s] so k_scan's per-j reads are
// coalesced over lane=s. Thread: s fast (tid&15), j slow (tid>>4).
// ---------------------------------------------------------------------------
__global__ __launch_bounds__(256) void k_gram(
    const float* __restrict__ e1, const float* __restrict__ e2,
    const float* __restrict__ r1, const float* __restrict__ r2,
    const float* __restrict__ r3, float* __restrict__ Wt) {
  int b = blockIdx.x / 9, m = blockIdx.x % 9;
  const float* sE = ((m < 6) ? e1 : e2) + (long)b * S_ * E_;
  const float* jE = ((m == 2 || m == 5 || m == 8) ? e2 : e1) + (long)b * S_ * E_;
  int sk = m / 3, jk = m % 3;
  const float* sR = ((sk == 0) ? r1 : (sk == 1) ? r2 : r3) + (long)b * S_ * R_;
  const float* jR = ((jk == 0) ? r1 : (jk == 1) ? r2 : r3) + (long)b * S_ * R_;

  __shared__ float Es[64][68], Ej[64][68], Rs[64][36], Rj[64][36];
  int tid = threadIdx.x;
  for (int i = tid; i < 1024; i += 256) {
    int row = i >> 4, c = i & 15;
    *(float4*)&Es[row][4 * c] = *(const float4*)(sE + row * 64 + 4 * c);
    *(float4*)&Ej[row][4 * c] = *(const float4*)(jE + row * 64 + 4 * c);
  }
  for (int i = tid; i < 512; i += 256) {
    int row = i >> 3, c = i & 7;
    *(float4*)&Rs[row][4 * c] = *(const float4*)(sR + row * 32 + 4 * c);
    *(float4*)&Rj[row][4 * c] = *(const float4*)(jR + row * 32 + 4 * c);
  }
  __syncthreads();

  int s0 = (tid & 15) * 4, j0 = (tid >> 4) * 4;
  float ed[4][4] = {}, rd[4][4] = {};  // [s][j]
#pragma unroll 4
  for (int k = 0; k < 16; ++k) {
    float4 es[4], ej[4];
#pragma unroll
    for (int i = 0; i < 4; ++i) {
      es[i] = *(const float4*)&Es[s0 + i][4 * k];
      ej[i] = *(const float4*)&Ej[j0 + i][4 * k];
    }
#pragma unroll
    for (int i = 0; i < 4; ++i)
#pragma unroll
      for (int j = 0; j < 4; ++j)
        ed[i][j] = fmaf(es[i].x, ej[j].x, fmaf(es[i].y, ej[j].y,
                   fmaf(es[i].z, ej[j].z, fmaf(es[i].w, ej[j].w, ed[i][j]))));
  }
#pragma unroll 4
  for (int k = 0; k < 8; ++k) {
    float4 rs[4], rj[4];
#pragma unroll
    for (int i = 0; i < 4; ++i) {
      rs[i] = *(const float4*)&Rs[s0 + i][4 * k];
      rj[i] = *(const float4*)&Rj[j0 + i][4 * k];
    }
#pragma unroll
    for (int i = 0; i < 4; ++i)
#pragma unroll
      for (int j = 0; j < 4; ++j)
        rd[i][j] = fmaf(rs[i].x, rj[j].x, fmaf(rs[i].y, rj[j].y,
                   fmaf(rs[i].z, rj[j].z, fmaf(rs[i].w, rj[j].w, rd[i][j]))));
  }
  float* wout = Wt + (long)(b * 9 + m) * 4096;
#pragma unroll
  for (int jj = 0; jj < 4; ++jj) {
    float4 o4 = make_float4(ed[0][jj] * rd[0][jj], ed[1][jj] * rd[1][jj],
                            ed[2][jj] * rd[2][jj], ed[3][jj] * rd[3][jj]);
    *(float4*)(wout + (j0 + jj) * 64 + s0) = o4;  // [j][s], s coalesced
  }
}

// ---------------------------------------------------------------------------
// K_scan v6: outer-product recurrence + LDS-staged transposed coefficients.
// lane = s. Per j: 9 stride-1 LDS reads (free), 6 readlane broadcasts (VALU),
// 18 fma, latch via ?:. Wt j-chunks (8 j x 64 s x 9 m = 18.4 KB) staged with
// dense 1KB loads, shared by the block's 4 waves (8 f's, same b).
// ---------------------------------------------------------------------------
__global__ __launch_bounds__(256) void k_scan(
    const float* __restrict__ e1g, const float* __restrict__ e2g,
    const float* __restrict__ Wt, float4* __restrict__ acd) {
  __shared__ float WtL[9 * 512];
  int b = blockIdx.x & 63;
  int g = blockIdx.x >> 6;         // 0..7
  int tid = threadIdx.x;
  int wv = tid >> 6;               // 0..3
  int lane = tid & 63;             // = s
  int f0 = g * 8 + wv * 2;
  int f1 = f0 + 1;
  const float* Wb = Wt + (long)b * 9 * 4096;
  long eoff = ((long)b * 64 + lane) * 64;
  float e1x = e1g[eoff + f0], e1y = e1g[eoff + f1];
  float e2x = e2g[eoff + f0], e2y = e2g[eoff + f1];

  float pW0 = 0.f, pM0 = 0.f, pB0 = 0.f;
  float pW1 = 0.f, pM1 = 0.f, pB1 = 0.f;
  float ca0 = e2x, cc0 = 0.f, cd0 = e1x;
  float ca1 = e2y, cc1 = 0.f, cd1 = e1y;
  float ka0 = 0.f, kc0 = 0.f, kd0 = 0.f;
  float ka1 = 0.f, kc1 = 0.f, kd1 = 0.f;

  for (int jc = 0; jc < 8; ++jc) {
    __syncthreads();
    // stage chunk: per m-plane, 512 contiguous floats (rows jc*8..+7 x 64 s)
    for (int i = tid; i < 1152; i += 256) {
      int m = i >> 7;                 // 128 float4 per plane
      int off = (i & 127) * 4;
      *(float4*)&WtL[m * 512 + off] = *(const float4*)(Wb + m * 4096 + jc * 512 + off);
    }
    __syncthreads();
#pragma unroll
    for (int jj = 0; jj < 8; ++jj) {
      int j = jc * 8 + jj;
      float wa = WtL[0 * 512 + jj * 64 + lane];
      float wc = WtL[1 * 512 + jj * 64 + lane];
      float wd = WtL[2 * 512 + jj * 64 + lane];
      float ma = WtL[3 * 512 + jj * 64 + lane];
      float mc = WtL[4 * 512 + jj * 64 + lane];
      float md = WtL[5 * 512 + jj * 64 + lane];
      float ba = WtL[6 * 512 + jj * 64 + lane];
      float bc = WtL[7 * 512 + jj * 64 + lane];
      float bd = WtL[8 * 512 + jj * 64 + lane];
      float aj0 = __int_as_float(__builtin_amdgcn_readlane(__float_as_int(ca0), j));
      float cj0 = __int_as_float(__builtin_amdgcn_readlane(__float_as_int(cc0), j));
      float dj0 = __int_as_float(__builtin_amdgcn_readlane(__float_as_int(cd0), j));
      float aj1 = __int_as_float(__builtin_amdgcn_readlane(__float_as_int(ca1), j));
      float cj1 = __int_as_float(__builtin_amdgcn_readlane(__float_as_int(cc1), j));
      float dj1 = __int_as_float(__builtin_amdgcn_readlane(__float_as_int(cd1), j));
      bool own = (lane == j);
      ka0 = own ? ca0 : ka0; kc0 = own ? cc0 : kc0; kd0 = own ? cd0 : kd0;
      ka1 = own ? ca1 : ka1; kc1 = own ? cc1 : kc1; kd1 = own ? cd1 : kd1;
      pW0 = fmaf(wa, aj0, pW0); pW0 = fmaf(wc, cj0, pW0); pW0 = fmaf(wd, dj0, pW0);
      pM0 = fmaf(ma, aj0, pM0); pM0 = fmaf(mc, cj0, pM0); pM0 = fmaf(md, dj0, pM0);
      pB0 = fmaf(ba, aj0, pB0); pB0 = fmaf(bc, cj0, pB0); pB0 = fmaf(bd, dj0, pB0);
      pW1 = fmaf(wa, aj1, pW1); pW1 = fmaf(wc, cj1, pW1); pW1 = fmaf(wd, dj1, pW1);
      pM1 = fmaf(ma, aj1, pM1); pM1 = fmaf(mc, cj1, pM1); pM1 = fmaf(md, dj1, pM1);
      pB1 = fmaf(ba, aj1, pB1); pB1 = fmaf(bc, cj1, pB1); pB1 = fmaf(bd, dj1, pB1);
      ca0 = e2x - pW0; cc0 = pW0 - pM0; cd0 = e1x - pB0;
      ca1 = e2y - pW1; cc1 = pW1 - pM1; cd1 = e1y - pB1;
    }
  }
  acd[eoff + f0] = make_float4(ka0, kc0, kd0, 0.f);
  acd[eoff + f1] = make_float4(ka1, kc1, kd1, 0.f);
}

// ---------------------------------------------------------------------------
// K_infer (R7 v2): 1024 threads per b; hist SoA in LDS.
// ---------------------------------------------------------------------------
__global__ __launch_bounds__(1024) void k_infer(
    const float4* __restrict__ acd,
    const float* __restrict__ e1, const float* __restrict__ e2,
    const float* __restrict__ r1, const float* __restrict__ r2,
    const float* __restrict__ r3,
    const float* __restrict__ qe1, const float* __restrict__ qr1,
    const float* __restrict__ qr2, const float* __restrict__ qr3,
    const float* __restrict__ lng, const float* __restrict__ lnb,
    float* __restrict__ isum) {
  int b = blockIdx.x, tid = threadIdx.x;
  __shared__ float hista[64 * 65], histc[64 * 65], histd[64 * 65];
  __shared__ float vlds[9 * 64];
  __shared__ float ivec[64];
  __shared__ float u1s[64], u2s[64];
  __shared__ float dsc[64];

  {
    const float4* ab = acd + (long)b * 4096;
    for (int idx = tid; idx < 4096; idx += 1024) {
      float4 hv = ab[idx];
      int j = idx >> 6, f = idx & 63;
      hista[j * 65 + f] = hv.x;
      histc[j * 65 + f] = hv.y;
      histd[j * 65 + f] = hv.z;
    }
  }
  if (tid < 576) {
    int pk = tid >> 6, j = tid & 63;
    int p = pk / 3, k = pk % 3;
    const float* rv = ((k == 0) ? r1 : (k == 1) ? r2 : r3) + ((long)b * 64 + j) * 32;
    const float* q = ((p == 0) ? qr1 : (p == 1) ? qr2 : qr3) + b * 32;
    float acc = 0.f;
#pragma unroll
    for (int t = 0; t < 8; ++t) {
      float4 rv4 = *(const float4*)(rv + 4 * t);
      float4 q4 = *(const float4*)(q + 4 * t);
      acc = fmaf(rv4.x, q4.x, fmaf(rv4.y, q4.y,
            fmaf(rv4.z, q4.z, fmaf(rv4.w, q4.w, acc))));
    }
    vlds[pk * 64 + j] = acc;
  }
  if (tid < 64) ivec[tid] = qe1[b * 64 + tid];
  __syncthreads();

  int f = tid >> 4, jsl = tid & 15;
  int dotd = tid >> 3, dt = tid & 7;
  int which = dotd >> 6, dj = dotd & 63;
  const float* erow = (which ? e2 : e1) + ((long)b * 64 + dj) * 64 + dt * 8;
  float isacc = 0.f;
  for (int p = 0; p < 3; ++p) {
    {
      float acc = 0.f;
#pragma unroll
      for (int t = 0; t < 8; ++t)
        acc = fmaf(erow[t], ivec[dt * 8 + t], acc);
      acc += __shfl_xor(acc, 1, 64);
      acc += __shfl_xor(acc, 2, 64);
      acc += __shfl_xor(acc, 4, 64);
      if (dt == 0) { if (which) u2s[dj] = acc; else u1s[dj] = acc; }
    }
    __syncthreads();
    float part = 0.f;
#pragma unroll
    for (int i = 0; i < 4; ++i) {
      int j = jsl * 4 + i;
      float ca = u1s[j] * vlds[(p * 3 + 0) * 64 + j];
      float cc = u1s[j] * vlds[(p * 3 + 1) * 64 + j];
      float cd = u2s[j] * vlds[(p * 3 + 2) * 64 + j];
      part = fmaf(ca, hista[j * 65 + f],
             fmaf(cc, histc[j * 65 + f],
             fmaf(cd, histd[j * 65 + f], part)));
    }
    part += __shfl_xor(part, 1, 64);
    part += __shfl_xor(part, 2, 64);
    part += __shfl_xor(part, 4, 64);
    part += __shfl_xor(part, 8, 64);
    if (jsl == 0) dsc[f] = part;
    __syncthreads();
    if (tid < 64) {
      float v = dsc[tid];
      float mu = v;
#pragma unroll
      for (int mm = 1; mm <= 32; mm <<= 1) mu += __shfl_xor(mu, mm, 64);
      mu *= (1.f / 64.f);
      float d = v - mu;
      float vr = d * d;
#pragma unroll
      for (int mm = 1; mm <= 32; mm <<= 1) vr += __shfl_xor(vr, mm, 64);
      vr *= (1.f / 64.f);
      float iv = d * (1.f / sqrtf(vr + 1e-5f)) * lng[p * 64 + tid] + lnb[p * 64 + tid];
      ivec[tid] = iv;
      isacc += iv;
    }
    __syncthreads();
  }
  if (tid < 64) isum[b * 64 + tid] = isacc;
}

// ---------------------------------------------------------------------------
// K5: out[b,v] = sum_e isum[b,e] * Z[e,v]
// ---------------------------------------------------------------------------
__global__ __launch_bounds__(256) void k_final(
    const float* __restrict__ isum, const float* __restrict__ Zm,
    float* __restrict__ out) {
  __shared__ float isT[64 * 68];
  int tid = threadIdx.x;
  for (int i = tid; i < 4096; i += 256) {
    int bb = i >> 6, e = i & 63;
    isT[e * 68 + bb] = isum[i];
  }
  __syncthreads();
  int tr = tid >> 4, tc = tid & 15;
  int v0 = blockIdx.x * 64 + tc * 4;
  float acc[4][4] = {};
#pragma unroll 2
  for (int e = 0; e < 64; ++e) {
    float4 a4 = *(const float4*)&isT[e * 68 + 4 * tr];
    float4 z4 = *(const float4*)(Zm + (long)e * V_ + v0);
    float as[4] = {a4.x, a4.y, a4.z, a4.w};
    float zs[4] = {z4.x, z4.y, z4.z, z4.w};
#pragma unroll
    for (int i = 0; i < 4; ++i)
#pragma unroll
      for (int j = 0; j < 4; ++j) acc[i][j] = fmaf(as[i], zs[j], acc[i][j]);
  }
#pragma unroll
  for (int i = 0; i < 4; ++i) {
    float4 o4 = make_float4(acc[i][0], acc[i][1], acc[i][2], acc[i][3]);
    *(float4*)(out + (long)(4 * tr + i) * V_ + v0) = o4;
  }
}

// ---------------------------------------------------------------------------
extern "C" void kernel_launch(void* const* d_in, const int* in_sizes, int n_in,
                              void* d_out, int out_size, void* d_ws, size_t ws_size,
                              hipStream_t stream) {
  const int* story = (const int*)d_in[0];
  const int* query = (const int*)d_in[1];
  const float* we = (const float*)d_in[2];
  const float* pe = (const float*)d_in[3];
  const float* ueW1 = (const float*)d_in[4];
  const float* ueb1 = (const float*)d_in[5];
  const float* ueW2 = (const float*)d_in[6];
  const float* ueb2 = (const float*)d_in[7];
  const float* urW1 = (const float*)d_in[8];
  const float* urb1 = (const float*)d_in[9];
  const float* urW2 = (const float*)d_in[10];
  const float* urb2 = (const float*)d_in[11];
  const float* ieW1 = (const float*)d_in[12];
  const float* ieb1 = (const float*)d_in[13];
  const float* ieW2 = (const float*)d_in[14];
  const float* ieb2 = (const float*)d_in[15];
  const float* irW1 = (const float*)d_in[16];
  const float* irb1 = (const float*)d_in[17];
  const float* irW2 = (const float*)d_in[18];
  const float* irb2 = (const float*)d_in[19];
  const float* lng = (const float*)d_in[20];
  const float* lnb = (const float*)d_in[21];
  const float* Zm = (const float*)d_in[22];

  float* ws = (float*)d_ws;
  float* X = ws;                        // 4160*128 = 532480
  float* e1 = X + 532480;               // 4160*64  = 266240
  float* e2 = e1 + 266240;              // 266240
  float* r1 = e2 + 266240;              // 4160*32  = 133120
  float* r2 = r1 + 133120;              // 133120
  float* r3 = r2 + 133120;              // 133120
  float* isum = r3 + 133120;            // 4096
  float* Wt = isum + 4096;              // 9*64*4096 = 2359296
  float4* acd = (float4*)(Wt + 2359296);  // 64*64*64 float4 = 4 MB
  float* qe1 = e1 + 4096 * 64;
  float* qr1 = r1 + 4096 * 32;
  float* qr2 = r2 + 4096 * 32;
  float* qr3 = r3 + 4096 * 32;
  float* outF = (float*)d_out;

  k_embed<<<4160, 128, 0, stream>>>(story, query, we, pe, X);
  k_mlp<<<130 * 5, 256, 0, stream>>>(X, ueW1, ueb1, ueW2, ueb2,
                                     urW1, urb1, urW2, urb2,
                                     ieW1, ieb1, ieW2, ieb2,
                                     irW1, irb1, irW2, irb2,
                                     e1, e2, r1, r2, r3);
  k_gram<<<64 * 9, 256, 0, stream>>>(e1, e2, r1, r2, r3, Wt);
  k_scan<<<512, 256, 0, stream>>>(e1, e2, Wt, acd);
  k_infer<<<B_, 1024, 0, stream>>>(acd, e1, e2, r1, r2, r3, qe1, qr1, qr2, qr3,
                                   lng, lnb, isum);
  k_final<<<V_ / 64, 256, 0, stream>>>(isum, Zm, outF);
}

// Round 9
// 221.879 us; speedup vs baseline: 1.4445x; 1.0087x over previous
//
#include <hip/hip_runtime.h>
#include <math.h>

// Problem constants
#define B_   64
#define S_   64
#define W_   12
#define V_   32000
#define SYM_ 128
#define HID_ 256
#define E_   64
#define R_   32

// ---------------------------------------------------------------------------
// K1: embedding sums for story (rows 0..4095) and query (rows 4096..4159)
// ---------------------------------------------------------------------------
__global__ __launch_bounds__(128) void k_embed(
    const int* __restrict__ story, const int* __restrict__ query,
    const float* __restrict__ we, const float* __restrict__ pe,
    float* __restrict__ X) {
  int row = blockIdx.x;
  int e = threadIdx.x;
  const int* idx = (row < 4096) ? story + row * W_ : query + (row - 4096) * W_;
  float acc = 0.f;
#pragma unroll
  for (int w = 0; w < W_; ++w)
    acc = fmaf(we[(long)idx[w] * SYM_ + e], pe[w * SYM_ + e], acc);
  X[row * SYM_ + e] = acc;
}

// ---------------------------------------------------------------------------
// K2 v6: LDS-GEMM MLP, bank-clean access patterns only.
// Block = (32-row tile, head); 650 blocks, 256 thr (4 waves).
// Wave w owns rows 8w..8w+7; lane l owns cols 4l..4l+3 (layer 1).
//  - W1L[k][256]: dense b128 reads (lane l -> 4l), the full-bandwidth pattern.
//  - XT[k][40]: two broadcast b128 reads per k (rows 8w / 8w+4).
//  - HT[row][260]: dense b128 writes per row; broadcast b128 reads in layer 2.
// Layer 2: lane = output col (E: 64 lanes; R: lanes 0-31), rows 8w..8w+7.
// ---------------------------------------------------------------------------
__global__ __launch_bounds__(256) void k_mlp(
    const float* __restrict__ X,
    const float* __restrict__ ueW1, const float* __restrict__ ueb1,
    const float* __restrict__ ueW2, const float* __restrict__ ueb2,
    const float* __restrict__ urW1, const float* __restrict__ urb1,
    const float* __restrict__ urW2, const float* __restrict__ urb2,
    const float* __restrict__ ieW1, const float* __restrict__ ieb1,
    const float* __restrict__ ieW2, const float* __restrict__ ieb2,
    const float* __restrict__ irW1, const float* __restrict__ irb1,
    const float* __restrict__ irW2, const float* __restrict__ irb2,
    float* __restrict__ oE0, float* __restrict__ oE1,
    float* __restrict__ oR0, float* __restrict__ oR1, float* __restrict__ oR2) {
  // staging phase: XT [0,1280) = [32 k][40]; W1L [1280, 9472) = [32 k][256]
  // H phase:       HT [0,8320) = [32 row][260]   (overlays, barrier-guarded)
  __shared__ float SM[9472];
  float* W1L = SM + 1280;

  int h = blockIdx.x % 5;
  int tile = blockIdx.x / 5;
  int rowbase = tile * 32;
  bool isQ = (rowbase >= 4096);
  bool isE = (h < 2);
  const float* W1 = isE ? (isQ ? ieW1 : ueW1) + h * (SYM_ * HID_)
                        : (isQ ? irW1 : urW1) + (h - 2) * (SYM_ * HID_);
  const float* b1 = isE ? (isQ ? ieb1 : ueb1) + h * HID_
                        : (isQ ? irb1 : urb1) + (h - 2) * HID_;
  const float* W2 = isE ? (isQ ? ieW2 : ueW2) + h * (HID_ * E_)
                        : (isQ ? irW2 : urW2) + (h - 2) * (HID_ * R_);
  const float* b2 = isE ? (isQ ? ieb2 : ueb2) + h * E_
                        : (isQ ? irb2 : urb2) + (h - 2) * R_;
  float* out = (h == 0) ? oE0 : (h == 1) ? oE1 : (h == 2) ? oR0 : (h == 3) ? oR1 : oR2;

  int tid = threadIdx.x;
  int wv = tid >> 6;    // wave: rows 8wv..8wv+7
  int l = tid & 63;     // lane: layer1 cols 4l..4l+3

  float a[8][4];
#pragma unroll
  for (int i = 0; i < 8; ++i)
#pragma unroll
    for (int q = 0; q < 4; ++q) a[i][q] = 0.f;

  for (int kc = 0; kc < 4; ++kc) {
    __syncthreads();
    // stage XT chunk: 32 rows x 32 k -> [k][row] stride 40
    {
      int row = tid >> 3, k4 = (tid & 7) * 4;
      float4 v = *(const float4*)(X + (long)(rowbase + row) * SYM_ + kc * 32 + k4);
      SM[(k4 + 0) * 40 + row] = v.x;
      SM[(k4 + 1) * 40 + row] = v.y;
      SM[(k4 + 2) * 40 + row] = v.z;
      SM[(k4 + 3) * 40 + row] = v.w;
    }
    // stage W1 chunk: 32 k x 256 c = 8192 contiguous floats, dense
    {
      const float* src = W1 + kc * 32 * HID_;
#pragma unroll
      for (int t = 0; t < 8; ++t)
        *(float4*)&W1L[(tid + 256 * t) * 4] = *(const float4*)(src + (tid + 256 * t) * 4);
    }
    __syncthreads();
#pragma unroll 4
    for (int k = 0; k < 32; ++k) {
      float4 wvv = *(const float4*)&W1L[k * 256 + 4 * l];       // dense b128
      float4 x0 = *(const float4*)&SM[k * 40 + 8 * wv];         // broadcast
      float4 x1 = *(const float4*)&SM[k * 40 + 8 * wv + 4];     // broadcast
      float xs[8] = {x0.x, x0.y, x0.z, x0.w, x1.x, x1.y, x1.z, x1.w};
#pragma unroll
      for (int i = 0; i < 8; ++i) {
        a[i][0] = fmaf(xs[i], wvv.x, a[i][0]);
        a[i][1] = fmaf(xs[i], wvv.y, a[i][1]);
        a[i][2] = fmaf(xs[i], wvv.z, a[i][2]);
        a[i][3] = fmaf(xs[i], wvv.w, a[i][3]);
      }
    }
  }
  __syncthreads();  // staging dead; HT overlays
  // bias + tanh -> HT[row][c] stride 260, dense b128 writes
  {
    float4 b1v = *(const float4*)(b1 + 4 * l);
#pragma unroll
    for (int i = 0; i < 8; ++i) {
      float4 hv = make_float4(tanhf(a[i][0] + b1v.x), tanhf(a[i][1] + b1v.y),
                              tanhf(a[i][2] + b1v.z), tanhf(a[i][3] + b1v.w));
      *(float4*)&SM[(8 * wv + i) * 260 + 4 * l] = hv;
    }
  }
  __syncthreads();
  // layer 2: lane = out col, rows 8wv..8wv+7
  if (isE) {
    float acc[8];
#pragma unroll
    for (int i = 0; i < 8; ++i) acc[i] = 0.f;
#pragma unroll 2
    for (int c4 = 0; c4 < 64; ++c4) {
      float w0 = W2[(long)(4 * c4 + 0) * E_ + l];
      float w1 = W2[(long)(4 * c4 + 1) * E_ + l];
      float w2 = W2[(long)(4 * c4 + 2) * E_ + l];
      float w3 = W2[(long)(4 * c4 + 3) * E_ + l];
#pragma unroll
      for (int i = 0; i < 8; ++i) {
        float4 hh = *(const float4*)&SM[(8 * wv + i) * 260 + 4 * c4];  // bcast
        acc[i] = fmaf(hh.x, w0, fmaf(hh.y, w1, fmaf(hh.z, w2, fmaf(hh.w, w3, acc[i]))));
      }
    }
    float bb = b2[l];
#pragma unroll
    for (int i = 0; i < 8; ++i)
      out[(long)(rowbase + 8 * wv + i) * E_ + l] = acc[i] + bb;
  } else {
    int lc = l & 31;
    float acc[8];
#pragma unroll
    for (int i = 0; i < 8; ++i) acc[i] = 0.f;
#pragma unroll 2
    for (int c4 = 0; c4 < 64; ++c4) {
      float w0 = W2[(long)(4 * c4 + 0) * R_ + lc];
      float w1 = W2[(long)(4 * c4 + 1) * R_ + lc];
      float w2 = W2[(long)(4 * c4 + 2) * R_ + lc];
      float w3 = W2[(long)(4 * c4 + 3) * R_ + lc];
#pragma unroll
      for (int i = 0; i < 8; ++i) {
        float4 hh = *(const float4*)&SM[(8 * wv + i) * 260 + 4 * c4];
        acc[i] = fmaf(hh.x, w0, fmaf(hh.y, w1, fmaf(hh.z, w2, fmaf(hh.w, w3, acc[i]))));
      }
    }
    if (l < 32) {
      float bb = b2[lc];
#pragma unroll
      for (int i = 0; i < 8; ++i)
        out[(long)(rowbase + 8 * wv + i) * R_ + lc] = acc[i] + bb;
    }
  }
}

// ---------------------------------------------------------------------------
// K_gram v2: writes TRANSPOSED Wt[b][m][j][s]  (unchanged from R8)
// ---------------------------------------------------------------------------
__global__ __launch_bounds__(256) void k_gram(
    const float* __restrict__ e1, const float* __restrict__ e2,
    const float* __restrict__ r1, const float* __restrict__ r2,
    const float* __restrict__ r3, float* __restrict__ Wt) {
  int b = blockIdx.x / 9, m = blockIdx.x % 9;
  const float* sE = ((m < 6) ? e1 : e2) + (long)b * S_ * E_;
  const float* jE = ((m == 2 || m == 5 || m == 8) ? e2 : e1) + (long)b * S_ * E_;
  int sk = m / 3, jk = m % 3;
  const float* sR = ((sk == 0) ? r1 : (sk == 1) ? r2 : r3) + (long)b * S_ * R_;
  const float* jR = ((jk == 0) ? r1 : (jk == 1) ? r2 : r3) + (long)b * S_ * R_;

  __shared__ float Es[64][68], Ej[64][68], Rs[64][36], Rj[64][36];
  int tid = threadIdx.x;
  for (int i = tid; i < 1024; i += 256) {
    int row = i >> 4, c = i & 15;
    *(float4*)&Es[row][4 * c] = *(const float4*)(sE + row * 64 + 4 * c);
    *(float4*)&Ej[row][4 * c] = *(const float4*)(jE + row * 64 + 4 * c);
  }
  for (int i = tid; i < 512; i += 256) {
    int row = i >> 3, c = i & 7;
    *(float4*)&Rs[row][4 * c] = *(const float4*)(sR + row * 32 + 4 * c);
    *(float4*)&Rj[row][4 * c] = *(const float4*)(jR + row * 32 + 4 * c);
  }
  __syncthreads();

  int s0 = (tid & 15) * 4, j0 = (tid >> 4) * 4;
  float ed[4][4] = {}, rd[4][4] = {};  // [s][j]
#pragma unroll 4
  for (int k = 0; k < 16; ++k) {
    float4 es[4], ej[4];
#pragma unroll
    for (int i = 0; i < 4; ++i) {
      es[i] = *(const float4*)&Es[s0 + i][4 * k];
      ej[i] = *(const float4*)&Ej[j0 + i][4 * k];
    }
#pragma unroll
    for (int i = 0; i < 4; ++i)
#pragma unroll
      for (int j = 0; j < 4; ++j)
        ed[i][j] = fmaf(es[i].x, ej[j].x, fmaf(es[i].y, ej[j].y,
                   fmaf(es[i].z, ej[j].z, fmaf(es[i].w, ej[j].w, ed[i][j]))));
  }
#pragma unroll 4
  for (int k = 0; k < 8; ++k) {
    float4 rs[4], rj[4];
#pragma unroll
    for (int i = 0; i < 4; ++i) {
      rs[i] = *(const float4*)&Rs[s0 + i][4 * k];
      rj[i] = *(const float4*)&Rj[j0 + i][4 * k];
    }
#pragma unroll
    for (int i = 0; i < 4; ++i)
#pragma unroll
      for (int j = 0; j < 4; ++j)
        rd[i][j] = fmaf(rs[i].x, rj[j].x, fmaf(rs[i].y, rj[j].y,
                   fmaf(rs[i].z, rj[j].z, fmaf(rs[i].w, rj[j].w, rd[i][j]))));
  }
  float* wout = Wt + (long)(b * 9 + m) * 4096;
#pragma unroll
  for (int jj = 0; jj < 4; ++jj) {
    float4 o4 = make_float4(ed[0][jj] * rd[0][jj], ed[1][jj] * rd[1][jj],
                            ed[2][jj] * rd[2][jj], ed[3][jj] * rd[3][jj]);
    *(float4*)(wout + (j0 + jj) * 64 + s0) = o4;  // [j][s]
  }
}

// ---------------------------------------------------------------------------
// K_scan v6 (unchanged from R8): outer-product recurrence, LDS-staged Wt.
// ---------------------------------------------------------------------------
__global__ __launch_bounds__(256) void k_scan(
    const float* __restrict__ e1g, const float* __restrict__ e2g,
    const float* __restrict__ Wt, float4* __restrict__ acd) {
  __shared__ float WtL[9 * 512];
  int b = blockIdx.x & 63;
  int g = blockIdx.x >> 6;
  int tid = threadIdx.x;
  int wv = tid >> 6;
  int lane = tid & 63;             // = s
  int f0 = g * 8 + wv * 2;
  int f1 = f0 + 1;
  const float* Wb = Wt + (long)b * 9 * 4096;
  long eoff = ((long)b * 64 + lane) * 64;
  float e1x = e1g[eoff + f0], e1y = e1g[eoff + f1];
  float e2x = e2g[eoff + f0], e2y = e2g[eoff + f1];

  float pW0 = 0.f, pM0 = 0.f, pB0 = 0.f;
  float pW1 = 0.f, pM1 = 0.f, pB1 = 0.f;
  float ca0 = e2x, cc0 = 0.f, cd0 = e1x;
  float ca1 = e2y, cc1 = 0.f, cd1 = e1y;
  float ka0 = 0.f, kc0 = 0.f, kd0 = 0.f;
  float ka1 = 0.f, kc1 = 0.f, kd1 = 0.f;

  for (int jc = 0; jc < 8; ++jc) {
    __syncthreads();
    for (int i = tid; i < 1152; i += 256) {
      int m = i >> 7;
      int off = (i & 127) * 4;
      *(float4*)&WtL[m * 512 + off] = *(const float4*)(Wb + m * 4096 + jc * 512 + off);
    }
    __syncthreads();
#pragma unroll
    for (int jj = 0; jj < 8; ++jj) {
      int j = jc * 8 + jj;
      float wa = WtL[0 * 512 + jj * 64 + lane];
      float wc = WtL[1 * 512 + jj * 64 + lane];
      float wd = WtL[2 * 512 + jj * 64 + lane];
      float ma = WtL[3 * 512 + jj * 64 + lane];
      float mc = WtL[4 * 512 + jj * 64 + lane];
      float md = WtL[5 * 512 + jj * 64 + lane];
      float ba = WtL[6 * 512 + jj * 64 + lane];
      float bc = WtL[7 * 512 + jj * 64 + lane];
      float bd = WtL[8 * 512 + jj * 64 + lane];
      float aj0 = __int_as_float(__builtin_amdgcn_readlane(__float_as_int(ca0), j));
      float cj0 = __int_as_float(__builtin_amdgcn_readlane(__float_as_int(cc0), j));
      float dj0 = __int_as_float(__builtin_amdgcn_readlane(__float_as_int(cd0), j));
      float aj1 = __int_as_float(__builtin_amdgcn_readlane(__float_as_int(ca1), j));
      float cj1 = __int_as_float(__builtin_amdgcn_readlane(__float_as_int(cc1), j));
      float dj1 = __int_as_float(__builtin_amdgcn_readlane(__float_as_int(cd1), j));
      bool own = (lane == j);
      ka0 = own ? ca0 : ka0; kc0 = own ? cc0 : kc0; kd0 = own ? cd0 : kd0;
      ka1 = own ? ca1 : ka1; kc1 = own ? cc1 : kc1; kd1 = own ? cd1 : kd1;
      pW0 = fmaf(wa, aj0, pW0); pW0 = fmaf(wc, cj0, pW0); pW0 = fmaf(wd, dj0, pW0);
      pM0 = fmaf(ma, aj0, pM0); pM0 = fmaf(mc, cj0, pM0); pM0 = fmaf(md, dj0, pM0);
      pB0 = fmaf(ba, aj0, pB0); pB0 = fmaf(bc, cj0, pB0); pB0 = fmaf(bd, dj0, pB0);
      pW1 = fmaf(wa, aj1, pW1); pW1 = fmaf(wc, cj1, pW1); pW1 = fmaf(wd, dj1, pW1);
      pM1 = fmaf(ma, aj1, pM1); pM1 = fmaf(mc, cj1, pM1); pM1 = fmaf(md, dj1, pM1);
      pB1 = fmaf(ba, aj1, pB1); pB1 = fmaf(bc, cj1, pB1); pB1 = fmaf(bd, dj1, pB1);
      ca0 = e2x - pW0; cc0 = pW0 - pM0; cd0 = e1x - pB0;
      ca1 = e2y - pW1; cc1 = pW1 - pM1; cd1 = e1y - pB1;
    }
  }
  acd[eoff + f0] = make_float4(ka0, kc0, kd0, 0.f);
  acd[eoff + f1] = make_float4(ka1, kc1, kd1, 0.f);
}

// ---------------------------------------------------------------------------
// K_infer (unchanged from R8)
// ---------------------------------------------------------------------------
__global__ __launch_bounds__(1024) void k_infer(
    const float4* __restrict__ acd,
    const float* __restrict__ e1, const float* __restrict__ e2,
    const float* __restrict__ r1, const float* __restrict__ r2,
    const float* __restrict__ r3,
    const float* __restrict__ qe1, const float* __restrict__ qr1,
    const float* __restrict__ qr2, const float* __restrict__ qr3,
    const float* __restrict__ lng, const float* __restrict__ lnb,
    float* __restrict__ isum) {
  int b = blockIdx.x, tid = threadIdx.x;
  __shared__ float hista[64 * 65], histc[64 * 65], histd[64 * 65];
  __shared__ float vlds[9 * 64];
  __shared__ float ivec[64];
  __shared__ float u1s[64], u2s[64];
  __shared__ float dsc[64];

  {
    const float4* ab = acd + (long)b * 4096;
    for (int idx = tid; idx < 4096; idx += 1024) {
      float4 hv = ab[idx];
      int j = idx >> 6, f = idx & 63;
      hista[j * 65 + f] = hv.x;
      histc[j * 65 + f] = hv.y;
      histd[j * 65 + f] = hv.z;
    }
  }
  if (tid < 576) {
    int pk = tid >> 6, j = tid & 63;
    int p = pk / 3, k = pk % 3;
    const float* rv = ((k == 0) ? r1 : (k == 1) ? r2 : r3) + ((long)b * 64 + j) * 32;
    const float* q = ((p == 0) ? qr1 : (p == 1) ? qr2 : qr3) + b * 32;
    float acc = 0.f;
#pragma unroll
    for (int t = 0; t < 8; ++t) {
      float4 rv4 = *(const float4*)(rv + 4 * t);
      float4 q4 = *(const float4*)(q + 4 * t);
      acc = fmaf(rv4.x, q4.x, fmaf(rv4.y, q4.y,
            fmaf(rv4.z, q4.z, fmaf(rv4.w, q4.w, acc))));
    }
    vlds[pk * 64 + j] = acc;
  }
  if (tid < 64) ivec[tid] = qe1[b * 64 + tid];
  __syncthreads();

  int f = tid >> 4, jsl = tid & 15;
  int dotd = tid >> 3, dt = tid & 7;
  int which = dotd >> 6, dj = dotd & 63;
  const float* erow = (which ? e2 : e1) + ((long)b * 64 + dj) * 64 + dt * 8;
  float isacc = 0.f;
  for (int p = 0; p < 3; ++p) {
    {
      float acc = 0.f;
#pragma unroll
      for (int t = 0; t < 8; ++t)
        acc = fmaf(erow[t], ivec[dt * 8 + t], acc);
      acc += __shfl_xor(acc, 1, 64);
      acc += __shfl_xor(acc, 2, 64);
      acc += __shfl_xor(acc, 4, 64);
      if (dt == 0) { if (which) u2s[dj] = acc; else u1s[dj] = acc; }
    }
    __syncthreads();
    float part = 0.f;
#pragma unroll
    for (int i = 0; i < 4; ++i) {
      int j = jsl * 4 + i;
      float ca = u1s[j] * vlds[(p * 3 + 0) * 64 + j];
      float cc = u1s[j] * vlds[(p * 3 + 1) * 64 + j];
      float cd = u2s[j] * vlds[(p * 3 + 2) * 64 + j];
      part = fmaf(ca, hista[j * 65 + f],
             fmaf(cc, histc[j * 65 + f],
             fmaf(cd, histd[j * 65 + f], part)));
    }
    part += __shfl_xor(part, 1, 64);
    part += __shfl_xor(part, 2, 64);
    part += __shfl_xor(part, 4, 64);
    part += __shfl_xor(part, 8, 64);
    if (jsl == 0) dsc[f] = part;
    __syncthreads();
    if (tid < 64) {
      float v = dsc[tid];
      float mu = v;
#pragma unroll
      for (int mm = 1; mm <= 32; mm <<= 1) mu += __shfl_xor(mu, mm, 64);
      mu *= (1.f / 64.f);
      float d = v - mu;
      float vr = d * d;
#pragma unroll
      for (int mm = 1; mm <= 32; mm <<= 1) vr += __shfl_xor(vr, mm, 64);
      vr *= (1.f / 64.f);
      float iv = d * (1.f / sqrtf(vr + 1e-5f)) * lng[p * 64 + tid] + lnb[p * 64 + tid];
      ivec[tid] = iv;
      isacc += iv;
    }
    __syncthreads();
  }
  if (tid < 64) isum[b * 64 + tid] = isacc;
}

// ---------------------------------------------------------------------------
// K5: out[b,v] = sum_e isum[b,e] * Z[e,v]   (unchanged)
// ---------------------------------------------------------------------------
__global__ __launch_bounds__(256) void k_final(
    const float* __restrict__ isum, const float* __restrict__ Zm,
    float* __restrict__ out) {
  __shared__ float isT[64 * 68];
  int tid = threadIdx.x;
  for (int i = tid; i < 4096; i += 256) {
    int bb = i >> 6, e = i & 63;
    isT[e * 68 + bb] = isum[i];
  }
  __syncthreads();
  int tr = tid >> 4, tc = tid & 15;
  int v0 = blockIdx.x * 64 + tc * 4;
  float acc[4][4] = {};
#pragma unroll 2
  for (int e = 0; e < 64; ++e) {
    float4 a4 = *(const float4*)&isT[e * 68 + 4 * tr];
    float4 z4 = *(const float4*)(Zm + (long)e * V_ + v0);
    float as[4] = {a4.x, a4.y, a4.z, a4.w};
    float zs[4] = {z4.x, z4.y, z4.z, z4.w};
#pragma unroll
    for (int i = 0; i < 4; ++i)
#pragma unroll
      for (int j = 0; j < 4; ++j) acc[i][j] = fmaf(as[i], zs[j], acc[i][j]);
  }
#pragma unroll
  for (int i = 0; i < 4; ++i) {
    float4 o4 = make_float4(acc[i][0], acc[i][1], acc[i][2], acc[i][3]);
    *(float4*)(out + (long)(4 * tr + i) * V_ + v0) = o4;
  }
}

// ---------------------------------------------------------------------------
extern "C" void kernel_launch(void* const* d_in, const int* in_sizes, int n_in,
                              void* d_out, int out_size, void* d_ws, size_t ws_size,
                              hipStream_t stream) {
  const int* story = (const int*)d_in[0];
  const int* query = (const int*)d_in[1];
  const float* we = (const float*)d_in[2];
  const float* pe = (const float*)d_in[3];
  const float* ueW1 = (const float*)d_in[4];
  const float* ueb1 = (const float*)d_in[5];
  const float* ueW2 = (const float*)d_in[6];
  const float* ueb2 = (const float*)d_in[7];
  const float* urW1 = (const float*)d_in[8];
  const float* urb1 = (const float*)d_in[9];
  const float* urW2 = (const float*)d_in[10];
  const float* urb2 = (const float*)d_in[11];
  const float* ieW1 = (const float*)d_in[12];
  const float* ieb1 = (const float*)d_in[13];
  const float* ieW2 = (const float*)d_in[14];
  const float* ieb2 = (const float*)d_in[15];
  const float* irW1 = (const float*)d_in[16];
  const float* irb1 = (const float*)d_in[17];
  const float* irW2 = (const float*)d_in[18];
  const float* irb2 = (const float*)d_in[19];
  const float* lng = (const float*)d_in[20];
  const float* lnb = (const float*)d_in[21];
  const float* Zm = (const float*)d_in[22];

  float* ws = (float*)d_ws;
  float* X = ws;                        // 4160*128 = 532480
  float* e1 = X + 532480;               // 4160*64  = 266240
  float* e2 = e1 + 266240;              // 266240
  float* r1 = e2 + 266240;              // 4160*32  = 133120
  float* r2 = r1 + 133120;              // 133120
  float* r3 = r2 + 133120;              // 133120
  float* isum = r3 + 133120;            // 4096
  float* Wt = isum + 4096;              // 9*64*4096 = 2359296
  float4* acd = (float4*)(Wt + 2359296);  // 64*64*64 float4 = 4 MB
  float* qe1 = e1 + 4096 * 64;
  float* qr1 = r1 + 4096 * 32;
  float* qr2 = r2 + 4096 * 32;
  float* qr3 = r3 + 4096 * 32;
  float* outF = (float*)d_out;

  k_embed<<<4160, 128, 0, stream>>>(story, query, we, pe, X);
  k_mlp<<<130 * 5, 256, 0, stream>>>(X, ueW1, ueb1, ueW2, ueb2,
                                     urW1, urb1, urW2, urb2,
                                     ieW1, ieb1, ieW2, ieb2,
                                     irW1, irb1, irW2, irb2,
                                     e1, e2, r1, r2, r3);
  k_gram<<<64 * 9, 256, 0, stream>>>(e1, e2, r1, r2, r3, Wt);
  k_scan<<<512, 256, 0, stream>>>(e1, e2, Wt, acd);
  k_infer<<<B_, 1024, 0, stream>>>(acd, e1, e2, r1, r2, r3, qe1, qr1, qr2, qr3,
                                   lng, lnb, isum);
  k_final<<<V_ / 64, 256, 0, stream>>>(isum, Zm, outF);
}

// Round 10
// 220.614 us; speedup vs baseline: 1.4527x; 1.0057x over previous
//
#include <hip/hip_runtime.h>
#include <math.h>

// Problem constants
#define B_   64
#define S_   64
#define W_   12
#define V_   32000
#define SYM_ 128
#define HID_ 256
#define E_   64
#define R_   32

// ---------------------------------------------------------------------------
// K1: embedding sums for story (rows 0..4095) and query (rows 4096..4159)
// ---------------------------------------------------------------------------
__global__ __launch_bounds__(128) void k_embed(
    const int* __restrict__ story, const int* __restrict__ query,
    const float* __restrict__ we, const float* __restrict__ pe,
    float* __restrict__ X) {
  int row = blockIdx.x;
  int e = threadIdx.x;
  const int* idx = (row < 4096) ? story + row * W_ : query + (row - 4096) * W_;
  float acc = 0.f;
#pragma unroll
  for (int w = 0; w < W_; ++w)
    acc = fmaf(we[(long)idx[w] * SYM_ + e], pe[w * SYM_ + e], acc);
  X[row * SYM_ + e] = acc;
}

// ---------------------------------------------------------------------------
// K2 v7: barrier-free layer 1.
// Block = (32-row tile, head); 650 blocks, 256 thr (4 waves).
// X tile staged ONCE in natural [row][k] (stride 136); layer-1 reads it as
// wave-uniform broadcast b128 and streams W1 DIRECT from global in the dense
// pattern (wave covers 1KB contiguous: 4 cache lines/request). No barriers
// inside the k-loop -> ILP hides L2 latency. Layer 2 as v6 (bank-clean).
// ---------------------------------------------------------------------------
__global__ __launch_bounds__(256) void k_mlp(
    const float* __restrict__ X,
    const float* __restrict__ ueW1, const float* __restrict__ ueb1,
    const float* __restrict__ ueW2, const float* __restrict__ ueb2,
    const float* __restrict__ urW1, const float* __restrict__ urb1,
    const float* __restrict__ urW2, const float* __restrict__ urb2,
    const float* __restrict__ ieW1, const float* __restrict__ ieb1,
    const float* __restrict__ ieW2, const float* __restrict__ ieb2,
    const float* __restrict__ irW1, const float* __restrict__ irb1,
    const float* __restrict__ irW2, const float* __restrict__ irb2,
    float* __restrict__ oE0, float* __restrict__ oE1,
    float* __restrict__ oR0, float* __restrict__ oR1, float* __restrict__ oR2) {
  // phase 1: XT [32 row][136] = 4352 floats.  phase 2: HT [32 row][260] = 8320.
  __shared__ float SM[8320];

  int h = blockIdx.x % 5;
  int tile = blockIdx.x / 5;
  int rowbase = tile * 32;
  bool isQ = (rowbase >= 4096);
  bool isE = (h < 2);
  const float* W1 = isE ? (isQ ? ieW1 : ueW1) + h * (SYM_ * HID_)
                        : (isQ ? irW1 : urW1) + (h - 2) * (SYM_ * HID_);
  const float* b1 = isE ? (isQ ? ieb1 : ueb1) + h * HID_
                        : (isQ ? irb1 : urb1) + (h - 2) * HID_;
  const float* W2 = isE ? (isQ ? ieW2 : ueW2) + h * (HID_ * E_)
                        : (isQ ? irW2 : urW2) + (h - 2) * (HID_ * R_);
  const float* b2 = isE ? (isQ ? ieb2 : ueb2) + h * E_
                        : (isQ ? irb2 : urb2) + (h - 2) * R_;
  float* out = (h == 0) ? oE0 : (h == 1) ? oE1 : (h == 2) ? oR0 : (h == 3) ? oR1 : oR2;

  int tid = threadIdx.x;
  int wv = tid >> 6;    // wave: rows 8wv..8wv+7
  int l = tid & 63;     // lane: cols 4l..4l+3 (layer 1)

  // stage X tile, natural layout [row][k], stride 136
#pragma unroll
  for (int c = 0; c < 4; ++c) {
    int i = tid + 256 * c;            // 0..1023 float4s
    int row = i >> 5, k4 = (i & 31) * 4;
    *(float4*)&SM[row * 136 + k4] = *(const float4*)(X + (long)(rowbase + row) * SYM_ + k4);
  }
  __syncthreads();

  float a[8][4];
#pragma unroll
  for (int i = 0; i < 8; ++i)
#pragma unroll
    for (int q = 0; q < 4; ++q) a[i][q] = 0.f;

  const float* W1p = W1 + 4 * l;
#pragma unroll 2
  for (int kg = 0; kg < 32; ++kg) {
    float4 w0 = *(const float4*)(W1p + (long)(4 * kg + 0) * HID_);
    float4 w1 = *(const float4*)(W1p + (long)(4 * kg + 1) * HID_);
    float4 w2 = *(const float4*)(W1p + (long)(4 * kg + 2) * HID_);
    float4 w3 = *(const float4*)(W1p + (long)(4 * kg + 3) * HID_);
    float4 xr[8];
#pragma unroll
    for (int i = 0; i < 8; ++i)
      xr[i] = *(const float4*)&SM[(8 * wv + i) * 136 + 4 * kg];  // broadcast b128
#pragma unroll
    for (int i = 0; i < 8; ++i) {
      a[i][0] = fmaf(xr[i].x, w0.x, a[i][0]);
      a[i][1] = fmaf(xr[i].x, w0.y, a[i][1]);
      a[i][2] = fmaf(xr[i].x, w0.z, a[i][2]);
      a[i][3] = fmaf(xr[i].x, w0.w, a[i][3]);
      a[i][0] = fmaf(xr[i].y, w1.x, a[i][0]);
      a[i][1] = fmaf(xr[i].y, w1.y, a[i][1]);
      a[i][2] = fmaf(xr[i].y, w1.z, a[i][2]);
      a[i][3] = fmaf(xr[i].y, w1.w, a[i][3]);
      a[i][0] = fmaf(xr[i].z, w2.x, a[i][0]);
      a[i][1] = fmaf(xr[i].z, w2.y, a[i][1]);
      a[i][2] = fmaf(xr[i].z, w2.z, a[i][2]);
      a[i][3] = fmaf(xr[i].z, w2.w, a[i][3]);
      a[i][0] = fmaf(xr[i].w, w3.x, a[i][0]);
      a[i][1] = fmaf(xr[i].w, w3.y, a[i][1]);
      a[i][2] = fmaf(xr[i].w, w3.z, a[i][2]);
      a[i][3] = fmaf(xr[i].w, w3.w, a[i][3]);
    }
  }
  __syncthreads();  // XT dead; HT overlays
  // bias + tanh -> HT[row][c] stride 260, dense b128 writes
  {
    float4 b1v = *(const float4*)(b1 + 4 * l);
#pragma unroll
    for (int i = 0; i < 8; ++i) {
      float4 hv = make_float4(tanhf(a[i][0] + b1v.x), tanhf(a[i][1] + b1v.y),
                              tanhf(a[i][2] + b1v.z), tanhf(a[i][3] + b1v.w));
      *(float4*)&SM[(8 * wv + i) * 260 + 4 * l] = hv;
    }
  }
  __syncthreads();
  // layer 2: lane = out col, rows 8wv..8wv+7
  if (isE) {
    float acc[8];
#pragma unroll
    for (int i = 0; i < 8; ++i) acc[i] = 0.f;
#pragma unroll 2
    for (int c4 = 0; c4 < 64; ++c4) {
      float w0 = W2[(long)(4 * c4 + 0) * E_ + l];
      float w1 = W2[(long)(4 * c4 + 1) * E_ + l];
      float w2 = W2[(long)(4 * c4 + 2) * E_ + l];
      float w3 = W2[(long)(4 * c4 + 3) * E_ + l];
#pragma unroll
      for (int i = 0; i < 8; ++i) {
        float4 hh = *(const float4*)&SM[(8 * wv + i) * 260 + 4 * c4];  // bcast
        acc[i] = fmaf(hh.x, w0, fmaf(hh.y, w1, fmaf(hh.z, w2, fmaf(hh.w, w3, acc[i]))));
      }
    }
    float bb = b2[l];
#pragma unroll
    for (int i = 0; i < 8; ++i)
      out[(long)(rowbase + 8 * wv + i) * E_ + l] = acc[i] + bb;
  } else {
    int lc = l & 31;
    float acc[8];
#pragma unroll
    for (int i = 0; i < 8; ++i) acc[i] = 0.f;
#pragma unroll 2
    for (int c4 = 0; c4 < 64; ++c4) {
      float w0 = W2[(long)(4 * c4 + 0) * R_ + lc];
      float w1 = W2[(long)(4 * c4 + 1) * R_ + lc];
      float w2 = W2[(long)(4 * c4 + 2) * R_ + lc];
      float w3 = W2[(long)(4 * c4 + 3) * R_ + lc];
#pragma unroll
      for (int i = 0; i < 8; ++i) {
        float4 hh = *(const float4*)&SM[(8 * wv + i) * 260 + 4 * c4];
        acc[i] = fmaf(hh.x, w0, fmaf(hh.y, w1, fmaf(hh.z, w2, fmaf(hh.w, w3, acc[i]))));
      }
    }
    if (l < 32) {
      float bb = b2[lc];
#pragma unroll
      for (int i = 0; i < 8; ++i)
        out[(long)(rowbase + 8 * wv + i) * R_ + lc] = acc[i] + bb;
    }
  }
}

// ---------------------------------------------------------------------------
// K_gram v2: writes TRANSPOSED Wt[b][m][j][s]  (unchanged)
// ---------------------------------------------------------------------------
__global__ __launch_bounds__(256) void k_gram(
    const float* __restrict__ e1, const float* __restrict__ e2,
    const float* __restrict__ r1, const float* __restrict__ r2,
    const float* __restrict__ r3, float* __restrict__ Wt) {
  int b = blockIdx.x / 9, m = blockIdx.x % 9;
  const float* sE = ((m < 6) ? e1 : e2) + (long)b * S_ * E_;
  const float* jE = ((m == 2 || m == 5 || m == 8) ? e2 : e1) + (long)b * S_ * E_;
  int sk = m / 3, jk = m % 3;
  const float* sR = ((sk == 0) ? r1 : (sk == 1) ? r2 : r3) + (long)b * S_ * R_;
  const float* jR = ((jk == 0) ? r1 : (jk == 1) ? r2 : r3) + (long)b * S_ * R_;

  __shared__ float Es[64][68], Ej[64][68], Rs[64][36], Rj[64][36];
  int tid = threadIdx.x;
  for (int i = tid; i < 1024; i += 256) {
    int row = i >> 4, c = i & 15;
    *(float4*)&Es[row][4 * c] = *(const float4*)(sE + row * 64 + 4 * c);
    *(float4*)&Ej[row][4 * c] = *(const float4*)(jE + row * 64 + 4 * c);
  }
  for (int i = tid; i < 512; i += 256) {
    int row = i >> 3, c = i & 7;
    *(float4*)&Rs[row][4 * c] = *(const float4*)(sR + row * 32 + 4 * c);
    *(float4*)&Rj[row][4 * c] = *(const float4*)(jR + row * 32 + 4 * c);
  }
  __syncthreads();

  int s0 = (tid & 15) * 4, j0 = (tid >> 4) * 4;
  float ed[4][4] = {}, rd[4][4] = {};  // [s][j]
#pragma unroll 4
  for (int k = 0; k < 16; ++k) {
    float4 es[4], ej[4];
#pragma unroll
    for (int i = 0; i < 4; ++i) {
      es[i] = *(const float4*)&Es[s0 + i][4 * k];
      ej[i] = *(const float4*)&Ej[j0 + i][4 * k];
    }
#pragma unroll
    for (int i = 0; i < 4; ++i)
#pragma unroll
      for (int j = 0; j < 4; ++j)
        ed[i][j] = fmaf(es[i].x, ej[j].x, fmaf(es[i].y, ej[j].y,
                   fmaf(es[i].z, ej[j].z, fmaf(es[i].w, ej[j].w, ed[i][j]))));
  }
#pragma unroll 4
  for (int k = 0; k < 8; ++k) {
    float4 rs[4], rj[4];
#pragma unroll
    for (int i = 0; i < 4; ++i) {
      rs[i] = *(const float4*)&Rs[s0 + i][4 * k];
      rj[i] = *(const float4*)&Rj[j0 + i][4 * k];
    }
#pragma unroll
    for (int i = 0; i < 4; ++i)
#pragma unroll
      for (int j = 0; j < 4; ++j)
        rd[i][j] = fmaf(rs[i].x, rj[j].x, fmaf(rs[i].y, rj[j].y,
                   fmaf(rs[i].z, rj[j].z, fmaf(rs[i].w, rj[j].w, rd[i][j]))));
  }
  float* wout = Wt + (long)(b * 9 + m) * 4096;
#pragma unroll
  for (int jj = 0; jj < 4; ++jj) {
    float4 o4 = make_float4(ed[0][jj] * rd[0][jj], ed[1][jj] * rd[1][jj],
                            ed[2][jj] * rd[2][jj], ed[3][jj] * rd[3][jj]);
    *(float4*)(wout + (j0 + jj) * 64 + s0) = o4;  // [j][s]
  }
}

// ---------------------------------------------------------------------------
// K_scan v6 (unchanged): outer-product recurrence, LDS-staged Wt.
// ---------------------------------------------------------------------------
__global__ __launch_bounds__(256) void k_scan(
    const float* __restrict__ e1g, const float* __restrict__ e2g,
    const float* __restrict__ Wt, float4* __restrict__ acd) {
  __shared__ float WtL[9 * 512];
  int b = blockIdx.x & 63;
  int g = blockIdx.x >> 6;
  int tid = threadIdx.x;
  int wv = tid >> 6;
  int lane = tid & 63;             // = s
  int f0 = g * 8 + wv * 2;
  int f1 = f0 + 1;
  const float* Wb = Wt + (long)b * 9 * 4096;
  long eoff = ((long)b * 64 + lane) * 64;
  float e1x = e1g[eoff + f0], e1y = e1g[eoff + f1];
  float e2x = e2g[eoff + f0], e2y = e2g[eoff + f1];

  float pW0 = 0.f, pM0 = 0.f, pB0 = 0.f;
  float pW1 = 0.f, pM1 = 0.f, pB1 = 0.f;
  float ca0 = e2x, cc0 = 0.f, cd0 = e1x;
  float ca1 = e2y, cc1 = 0.f, cd1 = e1y;
  float ka0 = 0.f, kc0 = 0.f, kd0 = 0.f;
  float ka1 = 0.f, kc1 = 0.f, kd1 = 0.f;

  for (int jc = 0; jc < 8; ++jc) {
    __syncthreads();
    for (int i = tid; i < 1152; i += 256) {
      int m = i >> 7;
      int off = (i & 127) * 4;
      *(float4*)&WtL[m * 512 + off] = *(const float4*)(Wb + m * 4096 + jc * 512 + off);
    }
    __syncthreads();
#pragma unroll
    for (int jj = 0; jj < 8; ++jj) {
      int j = jc * 8 + jj;
      float wa = WtL[0 * 512 + jj * 64 + lane];
      float wc = WtL[1 * 512 + jj * 64 + lane];
      float wd = WtL[2 * 512 + jj * 64 + lane];
      float ma = WtL[3 * 512 + jj * 64 + lane];
      float mc = WtL[4 * 512 + jj * 64 + lane];
      float md = WtL[5 * 512 + jj * 64 + lane];
      float ba = WtL[6 * 512 + jj * 64 + lane];
      float bc = WtL[7 * 512 + jj * 64 + lane];
      float bd = WtL[8 * 512 + jj * 64 + lane];
      float aj0 = __int_as_float(__builtin_amdgcn_readlane(__float_as_int(ca0), j));
      float cj0 = __int_as_float(__builtin_amdgcn_readlane(__float_as_int(cc0), j));
      float dj0 = __int_as_float(__builtin_amdgcn_readlane(__float_as_int(cd0), j));
      float aj1 = __int_as_float(__builtin_amdgcn_readlane(__float_as_int(ca1), j));
      float cj1 = __int_as_float(__builtin_amdgcn_readlane(__float_as_int(cc1), j));
      float dj1 = __int_as_float(__builtin_amdgcn_readlane(__float_as_int(cd1), j));
      bool own = (lane == j);
      ka0 = own ? ca0 : ka0; kc0 = own ? cc0 : kc0; kd0 = own ? cd0 : kd0;
      ka1 = own ? ca1 : ka1; kc1 = own ? cc1 : kc1; kd1 = own ? cd1 : kd1;
      pW0 = fmaf(wa, aj0, pW0); pW0 = fmaf(wc, cj0, pW0); pW0 = fmaf(wd, dj0, pW0);
      pM0 = fmaf(ma, aj0, pM0); pM0 = fmaf(mc, cj0, pM0); pM0 = fmaf(md, dj0, pM0);
      pB0 = fmaf(ba, aj0, pB0); pB0 = fmaf(bc, cj0, pB0); pB0 = fmaf(bd, dj0, pB0);
      pW1 = fmaf(wa, aj1, pW1); pW1 = fmaf(wc, cj1, pW1); pW1 = fmaf(wd, dj1, pW1);
      pM1 = fmaf(ma, aj1, pM1); pM1 = fmaf(mc, cj1, pM1); pM1 = fmaf(md, dj1, pM1);
      pB1 = fmaf(ba, aj1, pB1); pB1 = fmaf(bc, cj1, pB1); pB1 = fmaf(bd, dj1, pB1);
      ca0 = e2x - pW0; cc0 = pW0 - pM0; cd0 = e1x - pB0;
      ca1 = e2y - pW1; cc1 = pW1 - pM1; cd1 = e1y - pB1;
    }
  }
  acd[eoff + f0] = make_float4(ka0, kc0, kd0, 0.f);
  acd[eoff + f1] = make_float4(ka1, kc1, kd1, 0.f);
}

// ---------------------------------------------------------------------------
// K_infer (unchanged)
// ---------------------------------------------------------------------------
__global__ __launch_bounds__(1024) void k_infer(
    const float4* __restrict__ acd,
    const float* __restrict__ e1, const float* __restrict__ e2,
    const float* __restrict__ r1, const float* __restrict__ r2,
    const float* __restrict__ r3,
    const float* __restrict__ qe1, const float* __restrict__ qr1,
    const float* __restrict__ qr2, const float* __restrict__ qr3,
    const float* __restrict__ lng, const float* __restrict__ lnb,
    float* __restrict__ isum) {
  int b = blockIdx.x, tid = threadIdx.x;
  __shared__ float hista[64 * 65], histc[64 * 65], histd[64 * 65];
  __shared__ float vlds[9 * 64];
  __shared__ float ivec[64];
  __shared__ float u1s[64], u2s[64];
  __shared__ float dsc[64];

  {
    const float4* ab = acd + (long)b * 4096;
    for (int idx = tid; idx < 4096; idx += 1024) {
      float4 hv = ab[idx];
      int j = idx >> 6, f = idx & 63;
      hista[j * 65 + f] = hv.x;
      histc[j * 65 + f] = hv.y;
      histd[j * 65 + f] = hv.z;
    }
  }
  if (tid < 576) {
    int pk = tid >> 6, j = tid & 63;
    int p = pk / 3, k = pk % 3;
    const float* rv = ((k == 0) ? r1 : (k == 1) ? r2 : r3) + ((long)b * 64 + j) * 32;
    const float* q = ((p == 0) ? qr1 : (p == 1) ? qr2 : qr3) + b * 32;
    float acc = 0.f;
#pragma unroll
    for (int t = 0; t < 8; ++t) {
      float4 rv4 = *(const float4*)(rv + 4 * t);
      float4 q4 = *(const float4*)(q + 4 * t);
      acc = fmaf(rv4.x, q4.x, fmaf(rv4.y, q4.y,
            fmaf(rv4.z, q4.z, fmaf(rv4.w, q4.w, acc))));
    }
    vlds[pk * 64 + j] = acc;
  }
  if (tid < 64) ivec[tid] = qe1[b * 64 + tid];
  __syncthreads();

  int f = tid >> 4, jsl = tid & 15;
  int dotd = tid >> 3, dt = tid & 7;
  int which = dotd >> 6, dj = dotd & 63;
  const float* erow = (which ? e2 : e1) + ((long)b * 64 + dj) * 64 + dt * 8;
  float isacc = 0.f;
  for (int p = 0; p < 3; ++p) {
    {
      float acc = 0.f;
#pragma unroll
      for (int t = 0; t < 8; ++t)
        acc = fmaf(erow[t], ivec[dt * 8 + t], acc);
      acc += __shfl_xor(acc, 1, 64);
      acc += __shfl_xor(acc, 2, 64);
      acc += __shfl_xor(acc, 4, 64);
      if (dt == 0) { if (which) u2s[dj] = acc; else u1s[dj] = acc; }
    }
    __syncthreads();
    float part = 0.f;
#pragma unroll
    for (int i = 0; i < 4; ++i) {
      int j = jsl * 4 + i;
      float ca = u1s[j] * vlds[(p * 3 + 0) * 64 + j];
      float cc = u1s[j] * vlds[(p * 3 + 1) * 64 + j];
      float cd = u2s[j] * vlds[(p * 3 + 2) * 64 + j];
      part = fmaf(ca, hista[j * 65 + f],
             fmaf(cc, histc[j * 65 + f],
             fmaf(cd, histd[j * 65 + f], part)));
    }
    part += __shfl_xor(part, 1, 64);
    part += __shfl_xor(part, 2, 64);
    part += __shfl_xor(part, 4, 64);
    part += __shfl_xor(part, 8, 64);
    if (jsl == 0) dsc[f] = part;
    __syncthreads();
    if (tid < 64) {
      float v = dsc[tid];
      float mu = v;
#pragma unroll
      for (int mm = 1; mm <= 32; mm <<= 1) mu += __shfl_xor(mu, mm, 64);
      mu *= (1.f / 64.f);
      float d = v - mu;
      float vr = d * d;
#pragma unroll
      for (int mm = 1; mm <= 32; mm <<= 1) vr += __shfl_xor(vr, mm, 64);
      vr *= (1.f / 64.f);
      float iv = d * (1.f / sqrtf(vr + 1e-5f)) * lng[p * 64 + tid] + lnb[p * 64 + tid];
      ivec[tid] = iv;
      isacc += iv;
    }
    __syncthreads();
  }
  if (tid < 64) isum[b * 64 + tid] = isacc;
}

// ---------------------------------------------------------------------------
// K5: out[b,v] = sum_e isum[b,e] * Z[e,v]   (unchanged)
// ---------------------------------------------------------------------------
__global__ __launch_bounds__(256) void k_final(
    const float* __restrict__ isum, const float* __restrict__ Zm,
    float* __restrict__ out) {
  __shared__ float isT[64 * 68];
  int tid = threadIdx.x;
  for (int i = tid; i < 4096; i += 256) {
    int bb = i >> 6, e = i & 63;
    isT[e * 68 + bb] = isum[i];
  }
  __syncthreads();
  int tr = tid >> 4, tc = tid & 15;
  int v0 = blockIdx.x * 64 + tc * 4;
  float acc[4][4] = {};
#pragma unroll 2
  for (int e = 0; e < 64; ++e) {
    float4 a4 = *(const float4*)&isT[e * 68 + 4 * tr];
    float4 z4 = *(const float4*)(Zm + (long)e * V_ + v0);
    float as[4] = {a4.x, a4.y, a4.z, a4.w};
    float zs[4] = {z4.x, z4.y, z4.z, z4.w};
#pragma unroll
    for (int i = 0; i < 4; ++i)
#pragma unroll
      for (int j = 0; j < 4; ++j) acc[i][j] = fmaf(as[i], zs[j], acc[i][j]);
  }
#pragma unroll
  for (int i = 0; i < 4; ++i) {
    float4 o4 = make_float4(acc[i][0], acc[i][1], acc[i][2], acc[i][3]);
    *(float4*)(out + (long)(4 * tr + i) * V_ + v0) = o4;
  }
}

// ---------------------------------------------------------------------------
extern "C" void kernel_launch(void* const* d_in, const int* in_sizes, int n_in,
                              void* d_out, int out_size, void* d_ws, size_t ws_size,
                              hipStream_t stream) {
  const int* story = (const int*)d_in[0];
  const int* query = (const int*)d_in[1];
  const float* we = (const float*)d_in[2];
  const float* pe = (const float*)d_in[3];
  const float* ueW1 = (const float*)d_in[4];
  const float* ueb1 = (const float*)d_in[5];
  const float* ueW2 = (const float*)d_in[6];
  const float* ueb2 = (const float*)d_in[7];
  const float* urW1 = (const float*)d_in[8];
  const float* urb1 = (const float*)d_in[9];
  const float* urW2 = (const float*)d_in[10];
  const float* urb2 = (const float*)d_in[11];
  const float* ieW1 = (const float*)d_in[12];
  const float* ieb1 = (const float*)d_in[13];
  const float* ieW2 = (const float*)d_in[14];
  const float* ieb2 = (const float*)d_in[15];
  const float* irW1 = (const float*)d_in[16];
  const float* irb1 = (const float*)d_in[17];
  const float* irW2 = (const float*)d_in[18];
  const float* irb2 = (const float*)d_in[19];
  const float* lng = (const float*)d_in[20];
  const float* lnb = (const float*)d_in[21];
  const float* Zm = (const float*)d_in[22];

  float* ws = (float*)d_ws;
  float* X = ws;                        // 4160*128 = 532480
  float* e1 = X + 532480;               // 4160*64  = 266240
  float* e2 = e1 + 266240;              // 266240
  float* r1 = e2 + 266240;              // 4160*32  = 133120
  float* r2 = r1 + 133120;              // 133120
  float* r3 = r2 + 133120;              // 133120
  float* isum = r3 + 133120;            // 4096
  float* Wt = isum + 4096;              // 9*64*4096 = 2359296
  float4* acd = (float4*)(Wt + 2359296);  // 64*64*64 float4 = 4 MB
  float* qe1 = e1 + 4096 * 64;
  float* qr1 = r1 + 4096 * 32;
  float* qr2 = r2 + 4096 * 32;
  float* qr3 = r3 + 4096 * 32;
  float* outF = (float*)d_out;

  k_embed<<<4160, 128, 0, stream>>>(story, query, we, pe, X);
  k_mlp<<<130 * 5, 256, 0, stream>>>(X, ueW1, ueb1, ueW2, ueb2,
                                     urW1, urb1, urW2, urb2,
                                     ieW1, ieb1, ieW2, ieb2,
                                     irW1, irb1, irW2, irb2,
                                     e1, e2, r1, r2, r3);
  k_gram<<<64 * 9, 256, 0, stream>>>(e1, e2, r1, r2, r3, Wt);
  k_scan<<<512, 256, 0, stream>>>(e1, e2, Wt, acd);
  k_infer<<<B_, 1024, 0, stream>>>(acd, e1, e2, r1, r2, r3, qe1, qr1, qr2, qr3,
                                   lng, lnb, isum);
  k_final<<<V_ / 64, 256, 0, stream>>>(isum, Zm, outF);
}